// Round 5
// baseline (713.832 us; speedup 1.0000x reference)
//
#include <hip/hip_runtime.h>

// Problem constants (reference: N=50000 nodes, E=800000 edges, D=128, K=3)
#define Nn 50000
#define Ee 800000
#define Dd 128
#define Kk 3
#define TE 64    // rows per block tile
#define NT 256   // threads for CSR/pack kernels
#define NTM 512  // threads per MFMA block (8 waves; 4 blocks/CU = 32 waves)

// LDS bf16 tile row stride (ushorts): 128 + 8 pad
#define LSTR 136
// Per-matrix packed-weight slot: hi[16384] + lo[16384] ushorts
#define WSLOT 32768

// Bucket sort CSR build: bucket = node >> 8 (196 buckets for N=50000)
#define NBUK 196
#define SCH 2048                      // edges per sort block
#define SB ((Ee + SCH - 1) / SCH)     // 391 blocks per direction

typedef short sh8 __attribute__((ext_vector_type(8)));    // 8 bf16 (4 VGPRs)
typedef float f32x4 __attribute__((ext_vector_type(4)));  // MFMA C/D

// Split fp32 into bf16 hi (truncate) + bf16 lo (residual, truncate).
__device__ __forceinline__ ushort bfsplit(float x, float* rem) {
  const unsigned u = __float_as_uint(x);
  *rem = x - __uint_as_float(u & 0xffff0000u);
  return (ushort)(u >> 16);
}
__device__ __forceinline__ ushort bftrunc(float x) {
  return (ushort)(__float_as_uint(x) >> 16);
}
// round-to-nearest f32 -> bf16 (x >= 0, finite)
__device__ __forceinline__ ushort f32_to_bf16_rtn(float x) {
  const unsigned u = __float_as_uint(x);
  return (ushort)((u + 0x7fffu + ((u >> 16) & 1u)) >> 16);
}

// accumulate 8 bf16 packed in one uint4 into two float4 accumulators
__device__ __forceinline__ void acc8(const uint4 v, float4& a0, float4& a1) {
  a0.x += __uint_as_float(v.x << 16);
  a0.y += __uint_as_float(v.x & 0xffff0000u);
  a0.z += __uint_as_float(v.y << 16);
  a0.w += __uint_as_float(v.y & 0xffff0000u);
  a1.x += __uint_as_float(v.z << 16);
  a1.y += __uint_as_float(v.z & 0xffff0000u);
  a1.z += __uint_as_float(v.w << 16);
  a1.w += __uint_as_float(v.w & 0xffff0000u);
}

// 64x128x128 layer on MFMA 16x16x32_bf16, split-bf16 (3 products).
// 8 waves: wave w owns n-tile w (cols [16w,16w+16)); 4 m-tiles; acc[4].
// A frag: lane reads A[m=lane&15][k=(lane>>4)*8+j]  (ds_read_b128 Sh/Sl)
// B frag: packed global, [((wave*4+c)*64+lane)*8+j] — 8 waves tile the
// matrix exactly once (no duplicated weight reads).
#define MFMA_LAYER(WH, WL)                                                     \
  {                                                                            \
    _Pragma("unroll")                                                          \
    for (int c = 0; c < 4; ++c) {                                              \
      const sh8 bh = *(const sh8*)((WH) + ((wave * 4 + c) * 64 + lane) * 8);   \
      const sh8 bl = *(const sh8*)((WL) + ((wave * 4 + c) * 64 + lane) * 8);   \
      _Pragma("unroll")                                                        \
      for (int mt = 0; mt < 4; ++mt) {                                         \
        const int aoff = (mt * 16 + l15) * LSTR + c * 32 + q8 * 8;             \
        const sh8 ah = *(const sh8*)(Sh + aoff);                               \
        const sh8 al = *(const sh8*)(Sl + aoff);                               \
        acc[mt] = __builtin_amdgcn_mfma_f32_16x16x32_bf16(ah, bh, acc[mt], 0, 0, 0); \
        acc[mt] = __builtin_amdgcn_mfma_f32_16x16x32_bf16(al, bh, acc[mt], 0, 0, 0); \
        acc[mt] = __builtin_amdgcn_mfma_f32_16x16x32_bf16(ah, bl, acc[mt], 0, 0, 0); \
      }                                                                        \
    }                                                                          \
  }

#define ZERO_ACC                                                 \
  {                                                              \
    _Pragma("unroll")                                            \
    for (int mt = 0; mt < 4; ++mt) {                             \
      acc[mt][0] = 0.f; acc[mt][1] = 0.f;                        \
      acc[mt][2] = 0.f; acc[mt][3] = 0.f;                        \
    }                                                            \
  }

// hidden = relu(acc + b1) -> split hi/lo back into LDS (C layout -> A layout)
#define HIDDEN_TO_LDS(B1ptr)                                     \
  {                                                              \
    const float bb = (B1ptr)[w16 + l15];                         \
    _Pragma("unroll")                                            \
    for (int mt = 0; mt < 4; ++mt)                               \
      _Pragma("unroll")                                          \
      for (int rg = 0; rg < 4; ++rg) {                           \
        const int row = mt * 16 + q8 * 4 + rg;                   \
        const float h = fmaxf(acc[mt][rg] + bb, 0.f);            \
        float rm;                                                \
        const ushort hh = bfsplit(h, &rm);                       \
        const int off = row * LSTR + w16 + l15;                  \
        Sh[off] = hh;                                            \
        Sl[off] = bftrunc(rm);                                   \
      }                                                          \
  }

// stc (C-layout f32, bias included, signed) -> split into LDS A-layout
#define STC_TO_LDS                                               \
  {                                                              \
    _Pragma("unroll")                                            \
    for (int mt = 0; mt < 4; ++mt)                               \
      _Pragma("unroll")                                          \
      for (int rg = 0; rg < 4; ++rg) {                           \
        const int row = mt * 16 + q8 * 4 + rg;                   \
        float rm;                                                \
        const ushort hh = bfsplit(stc[mt][rg], &rm);             \
        const int off = row * LSTR + w16 + l15;                  \
        Sh[off] = hh;                                            \
        Sl[off] = bftrunc(rm);                                   \
      }                                                          \
  }

// stage rows [row0, row0+nrow) of row-major f32 X (stride Dd) into Sh/Sl split
#define STAGE_ROWS(Xptr)                                                       \
  {                                                                            \
    _Pragma("unroll")                                                          \
    for (int it = 0; it < (TE * 32 / NTM); ++it) {                             \
      const int i = t + NTM * it;                                              \
      const int r = i >> 5;                                                    \
      const int c4 = (i & 31) << 2;                                            \
      float4 v = make_float4(0.f, 0.f, 0.f, 0.f);                              \
      if (r < nrow) v = *(const float4*)((Xptr) + (size_t)(row0 + r) * Dd + c4); \
      ushort4 hv, lv; float rm;                                                \
      hv.x = bfsplit(v.x, &rm); lv.x = bftrunc(rm);                            \
      hv.y = bfsplit(v.y, &rm); lv.y = bftrunc(rm);                            \
      hv.z = bfsplit(v.z, &rm); lv.z = bftrunc(rm);                            \
      hv.w = bfsplit(v.w, &rm); lv.w = bftrunc(rm);                            \
      *(ushort4*)(&Sh[r * LSTR + c4]) = hv;                                    \
      *(ushort4*)(&Sl[r * LSTR + c4]) = lv;                                    \
    }                                                                          \
  }

#define MFMA_PRELUDE                                             \
  const int lane = t & 63;                                       \
  const int wave = t >> 6;                                       \
  const int l15 = lane & 15;                                     \
  const int q8 = lane >> 4;                                      \
  const int w16 = wave * 16;                                     \
  f32x4 acc[4];

// Per-direction parameter pack: packed hi bases (lo = +16384) + biases.
struct DirP {
  const ushort *u1, *u2, *p1, *p2;             // upd w1/w2, msg w1/w2 (packed)
  const float *ub1, *ub2, *pb1, *pb2;
};

// ---------------------------------------------------------------------------
// Fused st + round-1 messages (782 blocks, 8 waves)
// ---------------------------------------------------------------------------
__global__ __launch_bounds__(NTM) void stmsg_kernel(
    const float* __restrict__ X,
    const ushort* __restrict__ Wn1, const ushort* __restrict__ Wn2,
    const float* __restrict__ Bn1, const float* __restrict__ Bn2,
    DirP pf, DirP pb,
    float* __restrict__ st, ushort* __restrict__ Mf, ushort* __restrict__ Mb)
{
  __shared__ __align__(16) ushort Sbuf[2 * TE * LSTR];  // 34.8 KB
  ushort* Sh = Sbuf;
  ushort* Sl = Sbuf + TE * LSTR;
  const int t = threadIdx.x;
  const int row0 = blockIdx.x * TE;
  const int rem = Nn - row0;
  const int nrow = rem < TE ? rem : TE;

  STAGE_ROWS(X);
  __syncthreads();
  MFMA_PRELUDE;

  // ---- nt MLP -> stc ----
  ZERO_ACC;
  MFMA_LAYER(Wn1, Wn1 + 16384);
  __syncthreads();
  HIDDEN_TO_LDS(Bn1);
  __syncthreads();
  ZERO_ACC;
  MFMA_LAYER(Wn2, Wn2 + 16384);

  float stc[4][4];
  {
    const float b2 = Bn2[w16 + l15];
    #pragma unroll
    for (int mt = 0; mt < 4; ++mt)
      #pragma unroll
      for (int rg = 0; rg < 4; ++rg) {
        const int row = mt * 16 + q8 * 4 + rg;
        const float v = acc[mt][rg] + b2;
        stc[mt][rg] = v;
        if (row < nrow) st[(size_t)(row0 + row) * Dd + w16 + l15] = v;
      }
  }
  __syncthreads();  // hidden tile fully consumed

  // ---- fwd msg MLP on stc ----
  STC_TO_LDS;
  __syncthreads();
  ZERO_ACC;
  MFMA_LAYER(pf.p1, pf.p1 + 16384);
  __syncthreads();
  HIDDEN_TO_LDS(pf.pb1);
  __syncthreads();
  ZERO_ACC;
  MFMA_LAYER(pf.p2, pf.p2 + 16384);
  {
    const float b2 = pf.pb2[w16 + l15];
    #pragma unroll
    for (int mt = 0; mt < 4; ++mt)
      #pragma unroll
      for (int rg = 0; rg < 4; ++rg) {
        const int row = mt * 16 + q8 * 4 + rg;
        if (row < nrow)
          Mf[(size_t)(row0 + row) * Dd + w16 + l15] =
              f32_to_bf16_rtn(fmaxf(acc[mt][rg] + b2, 0.f));
      }
  }
  __syncthreads();

  // ---- bwd msg MLP on stc ----
  STC_TO_LDS;
  __syncthreads();
  ZERO_ACC;
  MFMA_LAYER(pb.p1, pb.p1 + 16384);
  __syncthreads();
  HIDDEN_TO_LDS(pb.pb1);
  __syncthreads();
  ZERO_ACC;
  MFMA_LAYER(pb.p2, pb.p2 + 16384);
  {
    const float b2 = pb.pb2[w16 + l15];
    #pragma unroll
    for (int mt = 0; mt < 4; ++mt)
      #pragma unroll
      for (int rg = 0; rg < 4; ++rg) {
        const int row = mt * 16 + q8 * 4 + rg;
        if (row < nrow)
          Mb[(size_t)(row0 + row) * Dd + w16 + l15] =
              f32_to_bf16_rtn(fmaxf(acc[mt][rg] + b2, 0.f));
      }
  }
}

// ---------------------------------------------------------------------------
// Fused per-round kernel, dual direction (2*782 blocks, 8 waves)
//
// Phase A: 8 threads per node row; thread o8 owns 16B chunks at bytes
// o8*16 and 128+o8*16 of each 256B row (octet covers 2 full lines per
// load instruction). Edge-unrolled x8 -> 16 outstanding 16B loads.
// ---------------------------------------------------------------------------
template <int DO_MSG>
__global__ __launch_bounds__(NTM) void aggupdmsg_kernel(
    const ushort* __restrict__ Min_f, const ushort* __restrict__ Min_b,
    const int* __restrict__ rp_f, const int* __restrict__ rp_b,
    const int* __restrict__ col_f, const int* __restrict__ col_b,
    const float* __restrict__ st,
    ushort* __restrict__ RMf, ushort* __restrict__ RMb,
    float* __restrict__ RYf, float* __restrict__ RYb, int rstride,
    DirP pf, DirP pb, int nhalf)
{
  __shared__ __align__(16) ushort Sbuf[2 * TE * LSTR];  // 34.8 KB
  ushort* Sh = Sbuf;
  ushort* Sl = Sbuf + TE * LSTR;
  const int t = threadIdx.x;
  const int dir = blockIdx.x >= nhalf;
  const int row0 = (blockIdx.x - dir * nhalf) * TE;
  const int rem = Nn - row0;
  const int nrow = rem < TE ? rem : TE;
  const DirP P = dir ? pb : pf;
  const ushort* Min = dir ? Min_b : Min_f;
  const int* rp = dir ? rp_b : rp_f;
  const int* col = dir ? col_b : col_f;
  ushort* RoutM = dir ? RMb : RMf;
  float* RoutY = dir ? RYb : RYf;
  const int sink = dir ? 0 : (Nn - 1);

  // ---- phase A: gather-sum of bf16 M rows, f32 accumulate ----
  {
    const int nr = t >> 3;           // tile row, 8 threads per row
    const int o8 = t & 7;            // 16B sub-chunk id
    const int ob = (t & 63) & ~7;    // octet base lane for shuffles
    // za[k]: k0 cols o8*8+0..3, k1 +4..7, k2 64+o8*8+0..3, k3 +4..7
    float4 za[4];
    #pragma unroll
    for (int i = 0; i < 4; ++i) za[i] = make_float4(0.f, 0.f, 0.f, 0.f);
    if (nr < nrow) {
      const int gnode = row0 + nr;
      int e = rp[gnode];
      const int ee = rp[gnode + 1];
      const ushort* Mo = Min + o8 * 8;   // o8*16 bytes into each row
      for (; e + 7 < ee; e += 8) {   // 16 outstanding 16B loads
        const int cm = col[e + o8];  // coalesced: octet reads 32B
        uint4 va[8], vb[8];
        #pragma unroll
        for (int k = 0; k < 8; ++k) {
          const int ck = __shfl(cm, ob + k);
          const ushort* rk = Mo + (size_t)ck * Dd;
          va[k] = *(const uint4*)(rk);
          vb[k] = *(const uint4*)(rk + 64);
        }
        #pragma unroll
        for (int k = 0; k < 8; ++k) {
          acc8(va[k], za[0], za[1]);
          acc8(vb[k], za[2], za[3]);
        }
      }
      for (; e < ee; ++e) {
        const ushort* rk = Mo + (size_t)col[e] * Dd;
        acc8(*(const uint4*)(rk), za[0], za[1]);
        acc8(*(const uint4*)(rk + 64), za[2], za[3]);
      }
    }
    #pragma unroll
    for (int k = 0; k < 4; ++k) {
      ushort4 hv, lv; float rm;
      hv.x = bfsplit(za[k].x, &rm); lv.x = bftrunc(rm);
      hv.y = bfsplit(za[k].y, &rm); lv.y = bftrunc(rm);
      hv.z = bfsplit(za[k].z, &rm); lv.z = bftrunc(rm);
      hv.w = bfsplit(za[k].w, &rm); lv.w = bftrunc(rm);
      const int c4 = (k >> 1) * 64 + o8 * 8 + (k & 1) * 4;
      *(ushort4*)(&Sh[nr * LSTR + c4]) = hv;
      *(ushort4*)(&Sl[nr * LSTR + c4]) = lv;
    }
  }
  __syncthreads();

  MFMA_PRELUDE;

  // ---- phase B: update MLP ----
  ZERO_ACC;
  MFMA_LAYER(P.u1, P.u1 + 16384);
  __syncthreads();
  HIDDEN_TO_LDS(P.ub1);
  __syncthreads();
  ZERO_ACC;
  MFMA_LAYER(P.u2, P.u2 + 16384);

  // y = st + relu(acc + ub2), y[sink-row contribution] zeroed
  {
    const float b2 = P.ub2[w16 + l15];
    if (DO_MSG) __syncthreads();  // all hidden reads done before overwrite
    #pragma unroll
    for (int mt = 0; mt < 4; ++mt)
      #pragma unroll
      for (int rg = 0; rg < 4; ++rg) {
        const int row = mt * 16 + q8 * 4 + rg;
        float v = 0.f;
        if (row < nrow) {
          const int gr = row0 + row;
          v = fmaxf(acc[mt][rg] + b2, 0.f);
          if (gr == sink) v = 0.f;
          v += st[(size_t)gr * Dd + w16 + l15];
        }
        if (DO_MSG) {
          float rm;
          const ushort hh = bfsplit(v, &rm);
          const int off = row * LSTR + w16 + l15;
          Sh[off] = hh;
          Sl[off] = bftrunc(rm);
        } else if (row < nrow) {
          RoutY[(size_t)(row0 + row) * rstride + w16 + l15] = v;
        }
      }
  }

  if (DO_MSG) {
    __syncthreads();
    // ---- phase C: msg MLP on y-tile ----
    ZERO_ACC;
    MFMA_LAYER(P.p1, P.p1 + 16384);
    __syncthreads();
    HIDDEN_TO_LDS(P.pb1);
    __syncthreads();
    ZERO_ACC;
    MFMA_LAYER(P.p2, P.p2 + 16384);

    const float b2 = P.pb2[w16 + l15];
    #pragma unroll
    for (int mt = 0; mt < 4; ++mt)
      #pragma unroll
      for (int rg = 0; rg < 4; ++rg) {
        const int row = mt * 16 + q8 * 4 + rg;
        if (row < nrow)
          RoutM[(size_t)(row0 + row) * Dd + w16 + l15] =
              f32_to_bf16_rtn(fmaxf(acc[mt][rg] + b2, 0.f));
      }
  }
}

// ---------------------------------------------------------------------------
// Weight packing: matrices -> B-fragment order, split hi/lo.
// ---------------------------------------------------------------------------
struct WPtrs { const float* w[10]; };

__global__ void pack_w_kernel(WPtrs P, ushort* __restrict__ out)
{
  const int id = blockIdx.x * blockDim.x + threadIdx.x;  // 0..16383
  const int mat = blockIdx.y;
  const int j = id & 7;
  const int lane = (id >> 3) & 63;
  const int ch = (id >> 9) & 3;
  const int nt = id >> 11;
  const int k = ch * 32 + (lane >> 4) * 8 + j;
  const int n = nt * 16 + (lane & 15);
  const float x = P.w[mat][k * Dd + n];
  float rm;
  const ushort h = bfsplit(x, &rm);
  out[(size_t)mat * WSLOT + id] = h;
  out[(size_t)mat * WSLOT + 16384 + id] = bftrunc(rm);
}

// ---------------------------------------------------------------------------
// CSR build via 2-level bucket sort (bucket = node >> 8, 196 buckets).
// pairs[dir][i] = (key << 16) | val  (both < 65536 since N = 50000).
// ---------------------------------------------------------------------------
__global__ __launch_bounds__(256) void csr_count(
    const int* __restrict__ src, const int* __restrict__ dst,
    int* __restrict__ bcnt)
{
  const int dirv = blockIdx.y;
  const int* key = dirv ? src : dst;
  __shared__ int h[NBUK];
  const int t = threadIdx.x;
  if (t < NBUK) h[t] = 0;
  __syncthreads();
  const int e0 = blockIdx.x * SCH;
  #pragma unroll
  for (int i = 0; i < SCH / 256; ++i) {
    const int e = e0 + i * 256 + t;
    if (e < Ee) atomicAdd(&h[key[e] >> 8], 1);
  }
  __syncthreads();
  if (t < NBUK && h[t] > 0) atomicAdd(&bcnt[dirv * 256 + t], h[t]);
}

__global__ __launch_bounds__(256) void csr_scan(
    const int* __restrict__ bcnt, int* __restrict__ bbase,
    int* __restrict__ bcur, int* __restrict__ rp)
{
  __shared__ int s[256];
  const int t = threadIdx.x;
  for (int y = 0; y < 2; ++y) {
    const int v = (t < NBUK) ? bcnt[y * 256 + t] : 0;
    s[t] = v;
    __syncthreads();
    for (int off = 1; off < 256; off <<= 1) {
      int x = s[t];
      if (t >= off) x += s[t - off];
      __syncthreads();
      s[t] = x;
      __syncthreads();
    }
    const int excl = s[t] - v;
    if (t < NBUK) { bbase[y * 257 + t] = excl; bcur[y * 256 + t] = excl; }
    if (t == NBUK - 1) bbase[y * 257 + NBUK] = s[t];
    if (t == 0) rp[y * (Nn + 1) + Nn] = Ee;
    __syncthreads();
  }
}

__global__ __launch_bounds__(256) void csr_scatter(
    const int* __restrict__ src, const int* __restrict__ dst,
    int* __restrict__ bcur, uint* __restrict__ pairs)
{
  const int dirv = blockIdx.y;
  const int* key = dirv ? src : dst;
  const int* val = dirv ? dst : src;
  __shared__ int lh[NBUK], gb[NBUK], lc[NBUK];
  const int t = threadIdx.x;
  if (t < NBUK) { lh[t] = 0; lc[t] = 0; }
  __syncthreads();
  const int e0 = blockIdx.x * SCH;
  int ks[SCH / 256], vs[SCH / 256];
  #pragma unroll
  for (int i = 0; i < SCH / 256; ++i) {
    const int e = e0 + i * 256 + t;
    ks[i] = (e < Ee) ? key[e] : -1;
    vs[i] = (e < Ee) ? val[e] : 0;
    if (ks[i] >= 0) atomicAdd(&lh[ks[i] >> 8], 1);
  }
  __syncthreads();
  if (t < NBUK && lh[t] > 0) gb[t] = atomicAdd(&bcur[dirv * 256 + t], lh[t]);
  __syncthreads();
  uint* pd = pairs + (size_t)dirv * Ee;
  #pragma unroll
  for (int i = 0; i < SCH / 256; ++i) {
    if (ks[i] >= 0) {
      const int b = ks[i] >> 8;
      const int r = atomicAdd(&lc[b], 1);
      pd[gb[b] + r] = ((uint)ks[i] << 16) | (uint)vs[i];
    }
  }
}

__global__ __launch_bounds__(256) void csr_final(
    const uint* __restrict__ pairs, const int* __restrict__ bbase,
    int* __restrict__ rp, int* __restrict__ col_f, int* __restrict__ col_b)
{
  const int dirv = blockIdx.y;
  const int b = blockIdx.x;
  const int base = bbase[dirv * 257 + b];
  const int cnt = bbase[dirv * 257 + b + 1] - base;
  const uint* pd = pairs + (size_t)dirv * Ee + base;
  int* colo = dirv ? col_b : col_f;
  __shared__ int h[256];
  __shared__ int s[256];
  const int t = threadIdx.x;
  h[t] = 0;
  __syncthreads();
  for (int i = t; i < cnt; i += 256) atomicAdd(&h[(pd[i] >> 16) & 255], 1);
  __syncthreads();
  const int v = h[t];
  s[t] = v;
  __syncthreads();
  for (int off = 1; off < 256; off <<= 1) {
    int x = s[t];
    if (t >= off) x += s[t - off];
    __syncthreads();
    s[t] = x;
    __syncthreads();
  }
  const int excl = s[t] - v;
  const int node = b * 256 + t;
  if (node < Nn) rp[dirv * (Nn + 1) + node] = base + excl;
  h[t] = excl;  // becomes per-node cursor
  __syncthreads();
  for (int i = t; i < cnt; i += 256) {
    const uint p = pd[i];
    const int k = (p >> 16) & 255;
    const int r = atomicAdd(&h[k], 1);
    colo[base + r] = (int)(p & 0xffffu);
  }
}

// ---------------------------------------------------------------------------
extern "C" void kernel_launch(void* const* d_in, const int* in_sizes, int n_in,
                              void* d_out, int out_size, void* d_ws, size_t ws_size,
                              hipStream_t stream)
{
  const float* feat = (const float*)d_in[0];
  const int*   src  = (const int*)d_in[1];
  const int*   dst  = (const int*)d_in[2];

  const float* W[5][4];
  for (int p = 0; p < 5; ++p)
    for (int q = 0; q < 4; ++q)
      W[p][q] = (const float*)d_in[3 + p * 4 + q];

  // workspace: st(f32) + 4x bf16 M arrays + CSR + packed weights
  float* st = (float*)d_ws;                          // [N,D] f32
  ushort* Mp_f = (ushort*)(st + (size_t)Nn * Dd);    // ping fwd [N,D] bf16
  ushort* Mp_b = Mp_f + (size_t)Nn * Dd;             // ping bwd
  ushort* Mq_f = Mp_b + (size_t)Nn * Dd;             // pong fwd
  ushort* Mq_b = Mq_f + (size_t)Nn * Dd;             // pong bwd
  int* ip       = (int*)(Mq_b + (size_t)Nn * Dd);
  int* rp_f     = ip;                 ip += Nn + 1;  // rp_b contiguous after
  int* rp_b     = ip;                 ip += Nn + 1;
  int* col_f    = ip;                 ip += Ee;
  int* col_b    = ip;                 ip += Ee;
  int* bcnt     = ip;                 ip += 2 * 256;
  int* bbase    = ip;                 ip += 2 * 257;
  int* bcur     = ip;                 ip += 2 * 256;
  ushort* Wp = (ushort*)(((uintptr_t)ip + 63) & ~(uintptr_t)63);  // 640 KB
  float* out = (float*)d_out;                        // [N, 2D] f32

  // pairs buffer (6.4 MB) aliases the Mq pong region: CSR build completes
  // (stream-ordered) before round 1 writes Mq.
  uint* pairs = (uint*)Mq_f;

  const int nodeBlocks = (Nn + TE - 1) / TE;    // 782
  const int dualBlocks = 2 * nodeBlocks;        // 1564

  // ---- pack weights ----
  WPtrs wpk;  // slots: 2p = W[p].w1, 2p+1 = W[p].w2
  for (int p = 0; p < 5; ++p) { wpk.w[2 * p] = W[p][0]; wpk.w[2 * p + 1] = W[p][2]; }
  pack_w_kernel<<<dim3(64, 10), NT, 0, stream>>>(wpk, Wp);

  // ---- CSR build via bucket sort ----
  hipMemsetAsync(bcnt, 0, 2 * 256 * sizeof(int), stream);
  csr_count<<<dim3(SB, 2), 256, 0, stream>>>(src, dst, bcnt);
  csr_scan<<<1, 256, 0, stream>>>(bcnt, bbase, bcur, rp_f);
  csr_scatter<<<dim3(SB, 2), 256, 0, stream>>>(src, dst, bcur, pairs);
  csr_final<<<dim3(NBUK, 2), 256, 0, stream>>>(pairs, bbase, rp_f, col_f, col_b);

  #define WS(m) (Wp + (size_t)(m) * WSLOT)
  // fwd: upd = fu (p=2), msg = fp (p=1); bwd: upd = bu (p=4), msg = bp (p=3)
  DirP Pf = { WS(4), WS(5), WS(2), WS(3), W[2][1], W[2][3], W[1][1], W[1][3] };
  DirP Pb = { WS(8), WS(9), WS(6), WS(7), W[4][1], W[4][3], W[3][1], W[3][3] };

  // ---- fused st + round-1 messages ----
  stmsg_kernel<<<nodeBlocks, NTM, 0, stream>>>(
      feat, WS(0), WS(1), W[0][1], W[0][3], Pf, Pb, st, Mp_f, Mp_b);

  // ---- round 1: agg+upd+msg, ping -> pong ----
  aggupdmsg_kernel<1><<<dualBlocks, NTM, 0, stream>>>(
      Mp_f, Mp_b, rp_f, rp_b, col_f, col_b, st,
      Mq_f, Mq_b, nullptr, nullptr, 0, Pf, Pb, nodeBlocks);

  // ---- round 2: agg+upd+msg, pong -> ping ----
  aggupdmsg_kernel<1><<<dualBlocks, NTM, 0, stream>>>(
      Mq_f, Mq_b, rp_f, rp_b, col_f, col_b, st,
      Mp_f, Mp_b, nullptr, nullptr, 0, Pf, Pb, nodeBlocks);

  // ---- round 3 (final): agg+upd, ping -> y into out column-halves ----
  aggupdmsg_kernel<0><<<dualBlocks, NTM, 0, stream>>>(
      Mp_f, Mp_b, rp_f, rp_b, col_f, col_b, st,
      nullptr, nullptr, out, out + Dd, 2 * Dd, Pf, Pb, nodeBlocks);

  #undef WS
}

// Round 7
// 664.375 us; speedup vs baseline: 1.0744x; 1.0744x over previous
//
#include <hip/hip_runtime.h>

// Problem constants (reference: N=50000 nodes, E=800000 edges, D=128, K=3)
#define Nn 50000
#define Ee 800000
#define Dd 128
#define Kk 3
#define TE 64    // rows per block tile (34.8 KB LDS -> 4 blocks/CU)
#define NT 256   // threads per block (4 waves)

// LDS bf16 tile row stride (ushorts): 128 + 8 pad
#define LSTR 136
// Per-matrix packed-weight slot: hi[16384] + lo[16384] ushorts
#define WSLOT 32768

// Bucket sort CSR build: bucket = node >> 8 (196 buckets for N=50000)
#define NBUK 196
#define SCH 2048                      // edges per sort block
#define SB ((Ee + SCH - 1) / SCH)     // 391 blocks per direction

typedef short sh8 __attribute__((ext_vector_type(8)));    // 8 bf16 (4 VGPRs)
typedef float f32x4 __attribute__((ext_vector_type(4)));  // MFMA C/D

// Split fp32 into bf16 hi (truncate) + bf16 lo (residual, truncate).
__device__ __forceinline__ ushort bfsplit(float x, float* rem) {
  const unsigned u = __float_as_uint(x);
  *rem = x - __uint_as_float(u & 0xffff0000u);
  return (ushort)(u >> 16);
}
__device__ __forceinline__ ushort bftrunc(float x) {
  return (ushort)(__float_as_uint(x) >> 16);
}
// round-to-nearest f32 -> bf16 (x >= 0, finite)
__device__ __forceinline__ ushort f32_to_bf16_rtn(float x) {
  const unsigned u = __float_as_uint(x);
  return (ushort)((u + 0x7fffu + ((u >> 16) & 1u)) >> 16);
}

// accumulate 8 bf16 packed in one uint4 into two float4 accumulators
__device__ __forceinline__ void acc8(const uint4 v, float4& a0, float4& a1) {
  a0.x += __uint_as_float(v.x << 16);
  a0.y += __uint_as_float(v.x & 0xffff0000u);
  a0.z += __uint_as_float(v.y << 16);
  a0.w += __uint_as_float(v.y & 0xffff0000u);
  a1.x += __uint_as_float(v.z << 16);
  a1.y += __uint_as_float(v.z & 0xffff0000u);
  a1.z += __uint_as_float(v.w << 16);
  a1.w += __uint_as_float(v.w & 0xffff0000u);
}

// 64x128x128 layer on MFMA 16x16x32_bf16, split-bf16 (3 products).
#define MFMA_LAYER(WH, WL)                                                     \
  {                                                                            \
    _Pragma("unroll")                                                          \
    for (int c = 0; c < 4; ++c) {                                              \
      const sh8 bh0 = *(const sh8*)((WH) + (((nt0    ) * 4 + c) * 64 + lane) * 8); \
      const sh8 bh1 = *(const sh8*)((WH) + (((nt0 + 1) * 4 + c) * 64 + lane) * 8); \
      const sh8 bl0 = *(const sh8*)((WL) + (((nt0    ) * 4 + c) * 64 + lane) * 8); \
      const sh8 bl1 = *(const sh8*)((WL) + (((nt0 + 1) * 4 + c) * 64 + lane) * 8); \
      _Pragma("unroll")                                                        \
      for (int mt = 0; mt < 4; ++mt) {                                         \
        const int aoff = (mt * 16 + l15) * LSTR + c * 32 + q8 * 8;             \
        const sh8 ah = *(const sh8*)(Sh + aoff);                               \
        const sh8 al = *(const sh8*)(Sl + aoff);                               \
        acc[mt][0] = __builtin_amdgcn_mfma_f32_16x16x32_bf16(ah, bh0, acc[mt][0], 0, 0, 0); \
        acc[mt][1] = __builtin_amdgcn_mfma_f32_16x16x32_bf16(ah, bh1, acc[mt][1], 0, 0, 0); \
        acc[mt][0] = __builtin_amdgcn_mfma_f32_16x16x32_bf16(al, bh0, acc[mt][0], 0, 0, 0); \
        acc[mt][1] = __builtin_amdgcn_mfma_f32_16x16x32_bf16(al, bh1, acc[mt][1], 0, 0, 0); \
        acc[mt][0] = __builtin_amdgcn_mfma_f32_16x16x32_bf16(ah, bl0, acc[mt][0], 0, 0, 0); \
        acc[mt][1] = __builtin_amdgcn_mfma_f32_16x16x32_bf16(ah, bl1, acc[mt][1], 0, 0, 0); \
      }                                                                        \
    }                                                                          \
  }

#define ZERO_ACC                                                 \
  {                                                              \
    _Pragma("unroll")                                            \
    for (int mt = 0; mt < 4; ++mt)                               \
      _Pragma("unroll")                                          \
      for (int nl = 0; nl < 2; ++nl) {                           \
        acc[mt][nl][0] = 0.f; acc[mt][nl][1] = 0.f;              \
        acc[mt][nl][2] = 0.f; acc[mt][nl][3] = 0.f;              \
      }                                                          \
  }

// hidden = relu(acc + b1) -> split hi/lo back into LDS (C layout -> A layout)
#define HIDDEN_TO_LDS(B1ptr)                                     \
  {                                                              \
    const float b1a = (B1ptr)[w32 + l15];                        \
    const float b1b = (B1ptr)[w32 + 16 + l15];                   \
    _Pragma("unroll")                                            \
    for (int mt = 0; mt < 4; ++mt)                               \
      _Pragma("unroll")                                          \
      for (int nl = 0; nl < 2; ++nl) {                           \
        const int col = w32 + nl * 16 + l15;                     \
        const float bb = nl ? b1b : b1a;                         \
        _Pragma("unroll")                                        \
        for (int rg = 0; rg < 4; ++rg) {                         \
          const int row = mt * 16 + q8 * 4 + rg;                 \
          const float h = fmaxf(acc[mt][nl][rg] + bb, 0.f);      \
          float rm;                                              \
          const ushort hh = bfsplit(h, &rm);                     \
          const int off = row * LSTR + col;                      \
          Sh[off] = hh;                                          \
          Sl[off] = bftrunc(rm);                                 \
        }                                                        \
      }                                                          \
  }

// stc (C-layout f32, bias included, signed) -> split into LDS A-layout
#define STC_TO_LDS                                               \
  {                                                              \
    _Pragma("unroll")                                            \
    for (int mt = 0; mt < 4; ++mt)                               \
      _Pragma("unroll")                                          \
      for (int nl = 0; nl < 2; ++nl) {                           \
        const int col = w32 + nl * 16 + l15;                     \
        _Pragma("unroll")                                        \
        for (int rg = 0; rg < 4; ++rg) {                         \
          const int row = mt * 16 + q8 * 4 + rg;                 \
          float rm;                                              \
          const ushort hh = bfsplit(stc[mt][nl][rg], &rm);       \
          const int off = row * LSTR + col;                      \
          Sh[off] = hh;                                          \
          Sl[off] = bftrunc(rm);                                 \
        }                                                        \
      }                                                          \
  }

// stage rows [row0, row0+nrow) of row-major f32 X (stride Dd) into Sh/Sl split
#define STAGE_ROWS(Xptr)                                                       \
  {                                                                            \
    _Pragma("unroll")                                                          \
    for (int it = 0; it < (TE * 32 / NT); ++it) {                              \
      const int i = t + NT * it;                                               \
      const int r = i >> 5;                                                    \
      const int c4 = (i & 31) << 2;                                            \
      float4 v = make_float4(0.f, 0.f, 0.f, 0.f);                              \
      if (r < nrow) v = *(const float4*)((Xptr) + (size_t)(row0 + r) * Dd + c4); \
      ushort4 hv, lv; float rm;                                                \
      hv.x = bfsplit(v.x, &rm); lv.x = bftrunc(rm);                            \
      hv.y = bfsplit(v.y, &rm); lv.y = bftrunc(rm);                            \
      hv.z = bfsplit(v.z, &rm); lv.z = bftrunc(rm);                            \
      hv.w = bfsplit(v.w, &rm); lv.w = bftrunc(rm);                            \
      *(ushort4*)(&Sh[r * LSTR + c4]) = hv;                                    \
      *(ushort4*)(&Sl[r * LSTR + c4]) = lv;                                    \
    }                                                                          \
  }

#define MFMA_PRELUDE                                             \
  const int lane = t & 63;                                       \
  const int wave = t >> 6;                                       \
  const int l15 = lane & 15;                                     \
  const int q8 = lane >> 4;                                      \
  const int w32 = wave * 32;                                     \
  const int nt0 = wave * 2;                                      \
  f32x4 acc[4][2];

// Per-direction parameter pack: packed hi bases (lo = +16384) + biases.
struct DirP {
  const ushort *u1, *u2, *p1, *p2;             // upd w1/w2, msg w1/w2 (packed)
  const float *ub1, *ub2, *pb1, *pb2;
};

// ---------------------------------------------------------------------------
// Fused st + round-1 messages (782 blocks)
// ---------------------------------------------------------------------------
__global__ __launch_bounds__(NT) void stmsg_kernel(
    const float* __restrict__ X,
    const ushort* __restrict__ Wn1, const ushort* __restrict__ Wn2,
    const float* __restrict__ Bn1, const float* __restrict__ Bn2,
    DirP pf, DirP pb,
    float* __restrict__ st, ushort* __restrict__ Mf, ushort* __restrict__ Mb)
{
  __shared__ __align__(16) ushort Sbuf[2 * TE * LSTR];  // 34.8 KB
  ushort* Sh = Sbuf;
  ushort* Sl = Sbuf + TE * LSTR;
  const int t = threadIdx.x;
  const int row0 = blockIdx.x * TE;
  const int rem = Nn - row0;
  const int nrow = rem < TE ? rem : TE;

  STAGE_ROWS(X);
  __syncthreads();
  MFMA_PRELUDE;

  // ---- nt MLP -> stc ----
  ZERO_ACC;
  MFMA_LAYER(Wn1, Wn1 + 16384);
  __syncthreads();
  HIDDEN_TO_LDS(Bn1);
  __syncthreads();
  ZERO_ACC;
  MFMA_LAYER(Wn2, Wn2 + 16384);

  float stc[4][2][4];
  {
    const float b2a = Bn2[w32 + l15];
    const float b2b = Bn2[w32 + 16 + l15];
    #pragma unroll
    for (int mt = 0; mt < 4; ++mt)
      #pragma unroll
      for (int nl = 0; nl < 2; ++nl) {
        const int col = w32 + nl * 16 + l15;
        const float bb = nl ? b2b : b2a;
        #pragma unroll
        for (int rg = 0; rg < 4; ++rg) {
          const int row = mt * 16 + q8 * 4 + rg;
          const float v = acc[mt][nl][rg] + bb;
          stc[mt][nl][rg] = v;
          if (row < nrow) st[(size_t)(row0 + row) * Dd + col] = v;
        }
      }
  }
  __syncthreads();  // hidden tile fully consumed

  // ---- fwd msg MLP on stc ----
  STC_TO_LDS;
  __syncthreads();
  ZERO_ACC;
  MFMA_LAYER(pf.p1, pf.p1 + 16384);
  __syncthreads();
  HIDDEN_TO_LDS(pf.pb1);
  __syncthreads();
  ZERO_ACC;
  MFMA_LAYER(pf.p2, pf.p2 + 16384);
  {
    const float b2a = pf.pb2[w32 + l15];
    const float b2b = pf.pb2[w32 + 16 + l15];
    #pragma unroll
    for (int mt = 0; mt < 4; ++mt)
      #pragma unroll
      for (int nl = 0; nl < 2; ++nl) {
        const int col = w32 + nl * 16 + l15;
        const float bb = nl ? b2b : b2a;
        #pragma unroll
        for (int rg = 0; rg < 4; ++rg) {
          const int row = mt * 16 + q8 * 4 + rg;
          if (row < nrow)
            Mf[(size_t)(row0 + row) * Dd + col] =
                f32_to_bf16_rtn(fmaxf(acc[mt][nl][rg] + bb, 0.f));
        }
      }
  }
  __syncthreads();

  // ---- bwd msg MLP on stc ----
  STC_TO_LDS;
  __syncthreads();
  ZERO_ACC;
  MFMA_LAYER(pb.p1, pb.p1 + 16384);
  __syncthreads();
  HIDDEN_TO_LDS(pb.pb1);
  __syncthreads();
  ZERO_ACC;
  MFMA_LAYER(pb.p2, pb.p2 + 16384);
  {
    const float b2a = pb.pb2[w32 + l15];
    const float b2b = pb.pb2[w32 + 16 + l15];
    #pragma unroll
    for (int mt = 0; mt < 4; ++mt)
      #pragma unroll
      for (int nl = 0; nl < 2; ++nl) {
        const int col = w32 + nl * 16 + l15;
        const float bb = nl ? b2b : b2a;
        #pragma unroll
        for (int rg = 0; rg < 4; ++rg) {
          const int row = mt * 16 + q8 * 4 + rg;
          if (row < nrow)
            Mb[(size_t)(row0 + row) * Dd + col] =
                f32_to_bf16_rtn(fmaxf(acc[mt][nl][rg] + bb, 0.f));
        }
      }
  }
}

// ---------------------------------------------------------------------------
// Fused per-round kernel, dual direction (2*782 blocks)
//
// Phase A (line-coalesced): 4 threads per node row; lane q4 of each quad
// owns the q4*16-byte sub-chunk of each 64B line. col[] lists are sorted
// ascending by src so all resident blocks sweep M in the same src order
// (same-XCD L2 keeps the sweep band hot -> latency-limited gather speeds up).
// ---------------------------------------------------------------------------
template <int DO_MSG>
__global__ __launch_bounds__(NT) void aggupdmsg_kernel(
    const ushort* __restrict__ Min_f, const ushort* __restrict__ Min_b,
    const int* __restrict__ rp_f, const int* __restrict__ rp_b,
    const int* __restrict__ col_f, const int* __restrict__ col_b,
    const float* __restrict__ st,
    ushort* __restrict__ RMf, ushort* __restrict__ RMb,
    float* __restrict__ RYf, float* __restrict__ RYb, int rstride,
    DirP pf, DirP pb, int nhalf)
{
  __shared__ __align__(16) ushort Sbuf[2 * TE * LSTR];  // 34.8 KB
  ushort* Sh = Sbuf;
  ushort* Sl = Sbuf + TE * LSTR;
  const int t = threadIdx.x;
  const int dir = blockIdx.x >= nhalf;
  const int row0 = (blockIdx.x - dir * nhalf) * TE;
  const int rem = Nn - row0;
  const int nrow = rem < TE ? rem : TE;
  const DirP P = dir ? pb : pf;
  const ushort* Min = dir ? Min_b : Min_f;
  const int* rp = dir ? rp_b : rp_f;
  const int* col = dir ? col_b : col_f;
  ushort* RoutM = dir ? RMb : RMf;
  float* RoutY = dir ? RYb : RYf;
  const int sink = dir ? 0 : (Nn - 1);

  // ---- phase A: gather-sum of bf16 M rows, f32 accumulate ----
  {
    const int nr = t >> 2;           // tile row, 4 threads per row
    const int q4 = t & 3;            // 16B sub-chunk within each 64B line
    const int qb = (t & 63) & 60;    // quad base lane for shuffles
    // za[2i+h]: cols i*32 + q4*8 + h*4 + (0..3)
    float4 za[8];
    #pragma unroll
    for (int i = 0; i < 8; ++i) za[i] = make_float4(0.f, 0.f, 0.f, 0.f);
    if (nr < nrow) {
      const int gnode = row0 + nr;
      int e = rp[gnode];
      const int ee = rp[gnode + 1];
      const ushort* Mq4 = Min + q4 * 8;   // q4*16 bytes into each row
      for (; e + 3 < ee; e += 4) {   // 16 independent 16B loads in flight
        const int cm = col[e + q4];  // coalesced: quad reads 16B
        const int c0 = __shfl(cm, qb);
        const int c1 = __shfl(cm, qb + 1);
        const int c2 = __shfl(cm, qb + 2);
        const int c3 = __shfl(cm, qb + 3);
        const ushort* r0 = Mq4 + (size_t)c0 * Dd;
        const ushort* r1 = Mq4 + (size_t)c1 * Dd;
        const ushort* r2 = Mq4 + (size_t)c2 * Dd;
        const ushort* r3 = Mq4 + (size_t)c3 * Dd;
        uint4 v0[4], v1[4], v2[4], v3[4];
        #pragma unroll
        for (int i = 0; i < 4; ++i) v0[i] = *(const uint4*)(r0 + i * 32);
        #pragma unroll
        for (int i = 0; i < 4; ++i) v1[i] = *(const uint4*)(r1 + i * 32);
        #pragma unroll
        for (int i = 0; i < 4; ++i) v2[i] = *(const uint4*)(r2 + i * 32);
        #pragma unroll
        for (int i = 0; i < 4; ++i) v3[i] = *(const uint4*)(r3 + i * 32);
        #pragma unroll
        for (int i = 0; i < 4; ++i) {
          acc8(v0[i], za[2 * i], za[2 * i + 1]);
          acc8(v1[i], za[2 * i], za[2 * i + 1]);
          acc8(v2[i], za[2 * i], za[2 * i + 1]);
          acc8(v3[i], za[2 * i], za[2 * i + 1]);
        }
      }
      for (; e < ee; ++e) {
        const ushort* r0 = Mq4 + (size_t)col[e] * Dd;
        #pragma unroll
        for (int i = 0; i < 4; ++i)
          acc8(*(const uint4*)(r0 + i * 32), za[2 * i], za[2 * i + 1]);
      }
    }
    #pragma unroll
    for (int k = 0; k < 8; ++k) {
      ushort4 hv, lv; float rm;
      hv.x = bfsplit(za[k].x, &rm); lv.x = bftrunc(rm);
      hv.y = bfsplit(za[k].y, &rm); lv.y = bftrunc(rm);
      hv.z = bfsplit(za[k].z, &rm); lv.z = bftrunc(rm);
      hv.w = bfsplit(za[k].w, &rm); lv.w = bftrunc(rm);
      const int c4 = (k >> 1) * 32 + q4 * 8 + (k & 1) * 4;
      *(ushort4*)(&Sh[nr * LSTR + c4]) = hv;
      *(ushort4*)(&Sl[nr * LSTR + c4]) = lv;
    }
  }
  __syncthreads();

  MFMA_PRELUDE;

  // ---- phase B: update MLP ----
  ZERO_ACC;
  MFMA_LAYER(P.u1, P.u1 + 16384);
  __syncthreads();
  HIDDEN_TO_LDS(P.ub1);
  __syncthreads();
  ZERO_ACC;
  MFMA_LAYER(P.u2, P.u2 + 16384);

  // y = st + relu(acc + ub2), y[sink-row contribution] zeroed
  {
    const float b2a = P.ub2[w32 + l15];
    const float b2b = P.ub2[w32 + 16 + l15];
    if (DO_MSG) __syncthreads();  // all hidden reads done before overwrite
    #pragma unroll
    for (int mt = 0; mt < 4; ++mt)
      #pragma unroll
      for (int nl = 0; nl < 2; ++nl) {
        const int col = w32 + nl * 16 + l15;
        const float bb = nl ? b2b : b2a;
        #pragma unroll
        for (int rg = 0; rg < 4; ++rg) {
          const int row = mt * 16 + q8 * 4 + rg;
          float v = 0.f;
          if (row < nrow) {
            const int gr = row0 + row;
            v = fmaxf(acc[mt][nl][rg] + bb, 0.f);
            if (gr == sink) v = 0.f;
            v += st[(size_t)gr * Dd + col];
          }
          if (DO_MSG) {
            float rm;
            const ushort hh = bfsplit(v, &rm);
            const int off = row * LSTR + col;
            Sh[off] = hh;
            Sl[off] = bftrunc(rm);
          } else if (row < nrow) {
            RoutY[(size_t)(row0 + row) * rstride + col] = v;
          }
        }
      }
  }

  if (DO_MSG) {
    __syncthreads();
    // ---- phase C: msg MLP on y-tile ----
    ZERO_ACC;
    MFMA_LAYER(P.p1, P.p1 + 16384);
    __syncthreads();
    HIDDEN_TO_LDS(P.pb1);
    __syncthreads();
    ZERO_ACC;
    MFMA_LAYER(P.p2, P.p2 + 16384);

    const float b2a = P.pb2[w32 + l15];
    const float b2b = P.pb2[w32 + 16 + l15];
    #pragma unroll
    for (int mt = 0; mt < 4; ++mt)
      #pragma unroll
      for (int nl = 0; nl < 2; ++nl) {
        const int col = w32 + nl * 16 + l15;
        const float bb = nl ? b2b : b2a;
        #pragma unroll
        for (int rg = 0; rg < 4; ++rg) {
          const int row = mt * 16 + q8 * 4 + rg;
          if (row < nrow)
            RoutM[(size_t)(row0 + row) * Dd + col] =
                f32_to_bf16_rtn(fmaxf(acc[mt][nl][rg] + bb, 0.f));
        }
      }
  }
}

// ---------------------------------------------------------------------------
// Weight packing: matrices -> B-fragment order, split hi/lo.
// ---------------------------------------------------------------------------
struct WPtrs { const float* w[10]; };

__global__ void pack_w_kernel(WPtrs P, ushort* __restrict__ out)
{
  const int id = blockIdx.x * blockDim.x + threadIdx.x;  // 0..16383
  const int mat = blockIdx.y;
  const int j = id & 7;
  const int lane = (id >> 3) & 63;
  const int ch = (id >> 9) & 3;
  const int nt = id >> 11;
  const int k = ch * 32 + (lane >> 4) * 8 + j;
  const int n = nt * 16 + (lane & 15);
  const float x = P.w[mat][k * Dd + n];
  float rm;
  const ushort h = bfsplit(x, &rm);
  out[(size_t)mat * WSLOT + id] = h;
  out[(size_t)mat * WSLOT + 16384 + id] = bftrunc(rm);
}

// ---------------------------------------------------------------------------
// CSR build via 2-level bucket sort (bucket = node >> 8, 196 buckets).
// pairs[dir][i] = (key << 16) | val  (both < 65536 since N = 50000).
// csr_final additionally sorts each node's adjacency ascending by src so
// all blocks sweep M in the same order during phase A (L2 sweep locality).
// ---------------------------------------------------------------------------
__global__ __launch_bounds__(256) void csr_count(
    const int* __restrict__ src, const int* __restrict__ dst,
    int* __restrict__ bcnt)
{
  const int dirv = blockIdx.y;
  const int* key = dirv ? src : dst;
  __shared__ int h[NBUK];
  const int t = threadIdx.x;
  if (t < NBUK) h[t] = 0;
  __syncthreads();
  const int e0 = blockIdx.x * SCH;
  #pragma unroll
  for (int i = 0; i < SCH / 256; ++i) {
    const int e = e0 + i * 256 + t;
    if (e < Ee) atomicAdd(&h[key[e] >> 8], 1);
  }
  __syncthreads();
  if (t < NBUK && h[t] > 0) atomicAdd(&bcnt[dirv * 256 + t], h[t]);
}

__global__ __launch_bounds__(256) void csr_scan(
    const int* __restrict__ bcnt, int* __restrict__ bbase,
    int* __restrict__ bcur, int* __restrict__ rp)
{
  __shared__ int s[256];
  const int t = threadIdx.x;
  for (int y = 0; y < 2; ++y) {
    const int v = (t < NBUK) ? bcnt[y * 256 + t] : 0;
    s[t] = v;
    __syncthreads();
    for (int off = 1; off < 256; off <<= 1) {
      int x = s[t];
      if (t >= off) x += s[t - off];
      __syncthreads();
      s[t] = x;
      __syncthreads();
    }
    const int excl = s[t] - v;
    if (t < NBUK) { bbase[y * 257 + t] = excl; bcur[y * 256 + t] = excl; }
    if (t == NBUK - 1) bbase[y * 257 + NBUK] = s[t];
    if (t == 0) rp[y * (Nn + 1) + Nn] = Ee;
    __syncthreads();
  }
}

__global__ __launch_bounds__(256) void csr_scatter(
    const int* __restrict__ src, const int* __restrict__ dst,
    int* __restrict__ bcur, uint* __restrict__ pairs)
{
  const int dirv = blockIdx.y;
  const int* key = dirv ? src : dst;
  const int* val = dirv ? dst : src;
  __shared__ int lh[NBUK], gb[NBUK], lc[NBUK];
  const int t = threadIdx.x;
  if (t < NBUK) { lh[t] = 0; lc[t] = 0; }
  __syncthreads();
  const int e0 = blockIdx.x * SCH;
  int ks[SCH / 256], vs[SCH / 256];
  #pragma unroll
  for (int i = 0; i < SCH / 256; ++i) {
    const int e = e0 + i * 256 + t;
    ks[i] = (e < Ee) ? key[e] : -1;
    vs[i] = (e < Ee) ? val[e] : 0;
    if (ks[i] >= 0) atomicAdd(&lh[ks[i] >> 8], 1);
  }
  __syncthreads();
  if (t < NBUK && lh[t] > 0) gb[t] = atomicAdd(&bcur[dirv * 256 + t], lh[t]);
  __syncthreads();
  uint* pd = pairs + (size_t)dirv * Ee;
  #pragma unroll
  for (int i = 0; i < SCH / 256; ++i) {
    if (ks[i] >= 0) {
      const int b = ks[i] >> 8;
      const int r = atomicAdd(&lc[b], 1);
      pd[gb[b] + r] = ((uint)ks[i] << 16) | (uint)vs[i];
    }
  }
}

__global__ __launch_bounds__(256) void csr_final(
    const uint* __restrict__ pairs, const int* __restrict__ bbase,
    int* __restrict__ rp, int* __restrict__ col_f, int* __restrict__ col_b)
{
  const int dirv = blockIdx.y;
  const int b = blockIdx.x;
  const int base = bbase[dirv * 257 + b];
  const int cnt = bbase[dirv * 257 + b + 1] - base;
  const uint* pd = pairs + (size_t)dirv * Ee + base;
  int* colo = dirv ? col_b : col_f;
  __shared__ int h[256];
  __shared__ int s[256];
  const int t = threadIdx.x;
  h[t] = 0;
  __syncthreads();
  for (int i = t; i < cnt; i += 256) atomicAdd(&h[(pd[i] >> 16) & 255], 1);
  __syncthreads();
  const int v = h[t];
  s[t] = v;
  __syncthreads();
  for (int off = 1; off < 256; off <<= 1) {
    int x = s[t];
    if (t >= off) x += s[t - off];
    __syncthreads();
    s[t] = x;
    __syncthreads();
  }
  const int excl = s[t] - v;
  const int node = b * 256 + t;
  if (node < Nn) rp[dirv * (Nn + 1) + node] = base + excl;
  h[t] = excl;  // becomes per-node cursor
  __syncthreads();
  for (int i = t; i < cnt; i += 256) {
    const uint p = pd[i];
    const int k = (p >> 16) & 255;
    const int r = atomicAdd(&h[k], 1);
    colo[base + r] = (int)(p & 0xffffu);
  }
  __syncthreads();
  // ---- per-node insertion sort ascending by src (1 thread per node) ----
  if (node < Nn && v > 1) {
    int* seg = colo + base + excl;
    for (int i = 1; i < v; ++i) {
      const int x = seg[i];
      int j = i - 1;
      while (j >= 0 && seg[j] > x) { seg[j + 1] = seg[j]; --j; }
      seg[j + 1] = x;
    }
  }
}

// ---------------------------------------------------------------------------
extern "C" void kernel_launch(void* const* d_in, const int* in_sizes, int n_in,
                              void* d_out, int out_size, void* d_ws, size_t ws_size,
                              hipStream_t stream)
{
  const float* feat = (const float*)d_in[0];
  const int*   src  = (const int*)d_in[1];
  const int*   dst  = (const int*)d_in[2];

  const float* W[5][4];
  for (int p = 0; p < 5; ++p)
    for (int q = 0; q < 4; ++q)
      W[p][q] = (const float*)d_in[3 + p * 4 + q];

  // workspace: st(f32) + 4x bf16 M arrays + CSR + packed weights
  float* st = (float*)d_ws;                          // [N,D] f32
  ushort* Mp_f = (ushort*)(st + (size_t)Nn * Dd);    // ping fwd [N,D] bf16
  ushort* Mp_b = Mp_f + (size_t)Nn * Dd;             // ping bwd
  ushort* Mq_f = Mp_b + (size_t)Nn * Dd;             // pong fwd
  ushort* Mq_b = Mq_f + (size_t)Nn * Dd;             // pong bwd
  int* ip       = (int*)(Mq_b + (size_t)Nn * Dd);
  int* rp_f     = ip;                 ip += Nn + 1;  // rp_b contiguous after
  int* rp_b     = ip;                 ip += Nn + 1;
  int* col_f    = ip;                 ip += Ee;
  int* col_b    = ip;                 ip += Ee;
  int* bcnt     = ip;                 ip += 2 * 256;
  int* bbase    = ip;                 ip += 2 * 257;
  int* bcur     = ip;                 ip += 2 * 256;
  ushort* Wp = (ushort*)(((uintptr_t)ip + 63) & ~(uintptr_t)63);  // 640 KB
  float* out = (float*)d_out;                        // [N, 2D] f32

  // pairs buffer (6.4 MB) aliases the Mq pong region: CSR build completes
  // (stream-ordered) before round 1 writes Mq.
  uint* pairs = (uint*)Mq_f;

  const int nodeBlocks = (Nn + TE - 1) / TE;    // 782
  const int dualBlocks = 2 * nodeBlocks;        // 1564

  // ---- pack weights ----
  WPtrs wpk;  // slots: 2p = W[p].w1, 2p+1 = W[p].w2
  for (int p = 0; p < 5; ++p) { wpk.w[2 * p] = W[p][0]; wpk.w[2 * p + 1] = W[p][2]; }
  pack_w_kernel<<<dim3(64, 10), NT, 0, stream>>>(wpk, Wp);

  // ---- CSR build via bucket sort ----
  hipMemsetAsync(bcnt, 0, 2 * 256 * sizeof(int), stream);
  csr_count<<<dim3(SB, 2), 256, 0, stream>>>(src, dst, bcnt);
  csr_scan<<<1, 256, 0, stream>>>(bcnt, bbase, bcur, rp_f);
  csr_scatter<<<dim3(SB, 2), 256, 0, stream>>>(src, dst, bcur, pairs);
  csr_final<<<dim3(NBUK, 2), 256, 0, stream>>>(pairs, bbase, rp_f, col_f, col_b);

  #define WS(m) (Wp + (size_t)(m) * WSLOT)
  // fwd: upd = fu (p=2), msg = fp (p=1); bwd: upd = bu (p=4), msg = bp (p=3)
  DirP Pf = { WS(4), WS(5), WS(2), WS(3), W[2][1], W[2][3], W[1][1], W[1][3] };
  DirP Pb = { WS(8), WS(9), WS(6), WS(7), W[4][1], W[4][3], W[3][1], W[3][3] };

  // ---- fused st + round-1 messages ----
  stmsg_kernel<<<nodeBlocks, NT, 0, stream>>>(
      feat, WS(0), WS(1), W[0][1], W[0][3], Pf, Pb, st, Mp_f, Mp_b);

  // ---- round 1: agg+upd+msg, ping -> pong ----
  aggupdmsg_kernel<1><<<dualBlocks, NT, 0, stream>>>(
      Mp_f, Mp_b, rp_f, rp_b, col_f, col_b, st,
      Mq_f, Mq_b, nullptr, nullptr, 0, Pf, Pb, nodeBlocks);

  // ---- round 2: agg+upd+msg, pong -> ping ----
  aggupdmsg_kernel<1><<<dualBlocks, NT, 0, stream>>>(
      Mq_f, Mq_b, rp_f, rp_b, col_f, col_b, st,
      Mp_f, Mp_b, nullptr, nullptr, 0, Pf, Pb, nodeBlocks);

  // ---- round 3 (final): agg+upd, ping -> y into out column-halves ----
  aggupdmsg_kernel<0><<<dualBlocks, NT, 0, stream>>>(
      Mp_f, Mp_b, rp_f, rp_b, col_f, col_b, st,
      nullptr, nullptr, out, out + Dd, 2 * Dd, Pf, Pb, nodeBlocks);

  #undef WS
}

// Round 8
// 609.799 us; speedup vs baseline: 1.1706x; 1.0895x over previous
//
#include <hip/hip_runtime.h>

// Problem constants (reference: N=50000 nodes, E=800000 edges, D=128, K=3)
#define Nn 50000
#define Ee 800000
#define Dd 128
#define Kk 3
#define TE 64    // rows per block tile (34.8 KB LDS -> 4 blocks/CU)
#define NT 256   // threads per block (4 waves)

// LDS bf16 tile row stride (ushorts): 128 + 8 pad
#define LSTR 136
// Per-matrix packed-weight slot: hi[16384] + lo[16384] ushorts
#define WSLOT 32768

// Bucket sort CSR build: bucket = node >> 8 (196 buckets for N=50000)
#define NBUK 196
#define SCH 2048                      // edges per sort block
#define SB ((Ee + SCH - 1) / SCH)     // 391 blocks per direction
#define FCAP 5632                     // csr_final LDS capacity (mean 4096, >20 sigma)

typedef short sh8 __attribute__((ext_vector_type(8)));    // 8 bf16 (4 VGPRs)
typedef float f32x4 __attribute__((ext_vector_type(4)));  // MFMA C/D

// Split fp32 into bf16 hi (truncate) + bf16 lo (residual, truncate).
__device__ __forceinline__ ushort bfsplit(float x, float* rem) {
  const unsigned u = __float_as_uint(x);
  *rem = x - __uint_as_float(u & 0xffff0000u);
  return (ushort)(u >> 16);
}
__device__ __forceinline__ ushort bftrunc(float x) {
  return (ushort)(__float_as_uint(x) >> 16);
}
// round-to-nearest f32 -> bf16 (x >= 0, finite)
__device__ __forceinline__ ushort f32_to_bf16_rtn(float x) {
  const unsigned u = __float_as_uint(x);
  return (ushort)((u + 0x7fffu + ((u >> 16) & 1u)) >> 16);
}

// accumulate 8 bf16 packed in one uint4 into two float4 accumulators
__device__ __forceinline__ void acc8(const uint4 v, float4& a0, float4& a1) {
  a0.x += __uint_as_float(v.x << 16);
  a0.y += __uint_as_float(v.x & 0xffff0000u);
  a0.z += __uint_as_float(v.y << 16);
  a0.w += __uint_as_float(v.y & 0xffff0000u);
  a1.x += __uint_as_float(v.z << 16);
  a1.y += __uint_as_float(v.z & 0xffff0000u);
  a1.z += __uint_as_float(v.w << 16);
  a1.w += __uint_as_float(v.w & 0xffff0000u);
}

// 64x128x128 layer on MFMA 16x16x32_bf16, split-bf16 (3 products).
#define MFMA_LAYER(WH, WL)                                                     \
  {                                                                            \
    _Pragma("unroll")                                                          \
    for (int c = 0; c < 4; ++c) {                                              \
      const sh8 bh0 = *(const sh8*)((WH) + (((nt0    ) * 4 + c) * 64 + lane) * 8); \
      const sh8 bh1 = *(const sh8*)((WH) + (((nt0 + 1) * 4 + c) * 64 + lane) * 8); \
      const sh8 bl0 = *(const sh8*)((WL) + (((nt0    ) * 4 + c) * 64 + lane) * 8); \
      const sh8 bl1 = *(const sh8*)((WL) + (((nt0 + 1) * 4 + c) * 64 + lane) * 8); \
      _Pragma("unroll")                                                        \
      for (int mt = 0; mt < 4; ++mt) {                                         \
        const int aoff = (mt * 16 + l15) * LSTR + c * 32 + q8 * 8;             \
        const sh8 ah = *(const sh8*)(Sh + aoff);                               \
        const sh8 al = *(const sh8*)(Sl + aoff);                               \
        acc[mt][0] = __builtin_amdgcn_mfma_f32_16x16x32_bf16(ah, bh0, acc[mt][0], 0, 0, 0); \
        acc[mt][1] = __builtin_amdgcn_mfma_f32_16x16x32_bf16(ah, bh1, acc[mt][1], 0, 0, 0); \
        acc[mt][0] = __builtin_amdgcn_mfma_f32_16x16x32_bf16(al, bh0, acc[mt][0], 0, 0, 0); \
        acc[mt][1] = __builtin_amdgcn_mfma_f32_16x16x32_bf16(al, bh1, acc[mt][1], 0, 0, 0); \
        acc[mt][0] = __builtin_amdgcn_mfma_f32_16x16x32_bf16(ah, bl0, acc[mt][0], 0, 0, 0); \
        acc[mt][1] = __builtin_amdgcn_mfma_f32_16x16x32_bf16(ah, bl1, acc[mt][1], 0, 0, 0); \
      }                                                                        \
    }                                                                          \
  }

#define ZERO_ACC                                                 \
  {                                                              \
    _Pragma("unroll")                                            \
    for (int mt = 0; mt < 4; ++mt)                               \
      _Pragma("unroll")                                          \
      for (int nl = 0; nl < 2; ++nl) {                           \
        acc[mt][nl][0] = 0.f; acc[mt][nl][1] = 0.f;              \
        acc[mt][nl][2] = 0.f; acc[mt][nl][3] = 0.f;              \
      }                                                          \
  }

// hidden = relu(acc + b1) -> split hi/lo back into LDS (C layout -> A layout)
#define HIDDEN_TO_LDS(B1ptr)                                     \
  {                                                              \
    const float b1a = (B1ptr)[w32 + l15];                        \
    const float b1b = (B1ptr)[w32 + 16 + l15];                   \
    _Pragma("unroll")                                            \
    for (int mt = 0; mt < 4; ++mt)                               \
      _Pragma("unroll")                                          \
      for (int nl = 0; nl < 2; ++nl) {                           \
        const int col = w32 + nl * 16 + l15;                     \
        const float bb = nl ? b1b : b1a;                         \
        _Pragma("unroll")                                        \
        for (int rg = 0; rg < 4; ++rg) {                         \
          const int row = mt * 16 + q8 * 4 + rg;                 \
          const float h = fmaxf(acc[mt][nl][rg] + bb, 0.f);      \
          float rm;                                              \
          const ushort hh = bfsplit(h, &rm);                     \
          const int off = row * LSTR + col;                      \
          Sh[off] = hh;                                          \
          Sl[off] = bftrunc(rm);                                 \
        }                                                        \
      }                                                          \
  }

// stc (C-layout f32, bias included, signed) -> split into LDS A-layout
#define STC_TO_LDS                                               \
  {                                                              \
    _Pragma("unroll")                                            \
    for (int mt = 0; mt < 4; ++mt)                               \
      _Pragma("unroll")                                          \
      for (int nl = 0; nl < 2; ++nl) {                           \
        const int col = w32 + nl * 16 + l15;                     \
        _Pragma("unroll")                                        \
        for (int rg = 0; rg < 4; ++rg) {                         \
          const int row = mt * 16 + q8 * 4 + rg;                 \
          float rm;                                              \
          const ushort hh = bfsplit(stc[mt][nl][rg], &rm);       \
          const int off = row * LSTR + col;                      \
          Sh[off] = hh;                                          \
          Sl[off] = bftrunc(rm);                                 \
        }                                                        \
      }                                                          \
  }

// stage rows [row0, row0+nrow) of row-major f32 X (stride Dd) into Sh/Sl split
#define STAGE_ROWS(Xptr)                                                       \
  {                                                                            \
    _Pragma("unroll")                                                          \
    for (int it = 0; it < (TE * 32 / NT); ++it) {                              \
      const int i = t + NT * it;                                               \
      const int r = i >> 5;                                                    \
      const int c4 = (i & 31) << 2;                                            \
      float4 v = make_float4(0.f, 0.f, 0.f, 0.f);                              \
      if (r < nrow) v = *(const float4*)((Xptr) + (size_t)(row0 + r) * Dd + c4); \
      ushort4 hv, lv; float rm;                                                \
      hv.x = bfsplit(v.x, &rm); lv.x = bftrunc(rm);                            \
      hv.y = bfsplit(v.y, &rm); lv.y = bftrunc(rm);                            \
      hv.z = bfsplit(v.z, &rm); lv.z = bftrunc(rm);                            \
      hv.w = bfsplit(v.w, &rm); lv.w = bftrunc(rm);                            \
      *(ushort4*)(&Sh[r * LSTR + c4]) = hv;                                    \
      *(ushort4*)(&Sl[r * LSTR + c4]) = lv;                                    \
    }                                                                          \
  }

#define MFMA_PRELUDE                                             \
  const int lane = t & 63;                                       \
  const int wave = t >> 6;                                       \
  const int l15 = lane & 15;                                     \
  const int q8 = lane >> 4;                                      \
  const int w32 = wave * 32;                                     \
  const int nt0 = wave * 2;                                      \
  f32x4 acc[4][2];

// Per-direction parameter pack: packed hi bases (lo = +16384) + biases.
struct DirP {
  const ushort *u1, *u2, *p1, *p2;             // upd w1/w2, msg w1/w2 (packed)
  const float *ub1, *ub2, *pb1, *pb2;
};

// ---------------------------------------------------------------------------
// Fused st + round-1 messages (782 blocks)
// ---------------------------------------------------------------------------
__global__ __launch_bounds__(NT) void stmsg_kernel(
    const float* __restrict__ X,
    const ushort* __restrict__ Wn1, const ushort* __restrict__ Wn2,
    const float* __restrict__ Bn1, const float* __restrict__ Bn2,
    DirP pf, DirP pb,
    float* __restrict__ st, ushort* __restrict__ Mf, ushort* __restrict__ Mb)
{
  __shared__ __align__(16) ushort Sbuf[2 * TE * LSTR];  // 34.8 KB
  ushort* Sh = Sbuf;
  ushort* Sl = Sbuf + TE * LSTR;
  const int t = threadIdx.x;
  const int row0 = blockIdx.x * TE;
  const int rem = Nn - row0;
  const int nrow = rem < TE ? rem : TE;

  STAGE_ROWS(X);
  __syncthreads();
  MFMA_PRELUDE;

  // ---- nt MLP -> stc ----
  ZERO_ACC;
  MFMA_LAYER(Wn1, Wn1 + 16384);
  __syncthreads();
  HIDDEN_TO_LDS(Bn1);
  __syncthreads();
  ZERO_ACC;
  MFMA_LAYER(Wn2, Wn2 + 16384);

  float stc[4][2][4];
  {
    const float b2a = Bn2[w32 + l15];
    const float b2b = Bn2[w32 + 16 + l15];
    #pragma unroll
    for (int mt = 0; mt < 4; ++mt)
      #pragma unroll
      for (int nl = 0; nl < 2; ++nl) {
        const int col = w32 + nl * 16 + l15;
        const float bb = nl ? b2b : b2a;
        #pragma unroll
        for (int rg = 0; rg < 4; ++rg) {
          const int row = mt * 16 + q8 * 4 + rg;
          const float v = acc[mt][nl][rg] + bb;
          stc[mt][nl][rg] = v;
          if (row < nrow) st[(size_t)(row0 + row) * Dd + col] = v;
        }
      }
  }
  __syncthreads();  // hidden tile fully consumed

  // ---- fwd msg MLP on stc ----
  STC_TO_LDS;
  __syncthreads();
  ZERO_ACC;
  MFMA_LAYER(pf.p1, pf.p1 + 16384);
  __syncthreads();
  HIDDEN_TO_LDS(pf.pb1);
  __syncthreads();
  ZERO_ACC;
  MFMA_LAYER(pf.p2, pf.p2 + 16384);
  {
    const float b2a = pf.pb2[w32 + l15];
    const float b2b = pf.pb2[w32 + 16 + l15];
    #pragma unroll
    for (int mt = 0; mt < 4; ++mt)
      #pragma unroll
      for (int nl = 0; nl < 2; ++nl) {
        const int col = w32 + nl * 16 + l15;
        const float bb = nl ? b2b : b2a;
        #pragma unroll
        for (int rg = 0; rg < 4; ++rg) {
          const int row = mt * 16 + q8 * 4 + rg;
          if (row < nrow)
            Mf[(size_t)(row0 + row) * Dd + col] =
                f32_to_bf16_rtn(fmaxf(acc[mt][nl][rg] + bb, 0.f));
        }
      }
  }
  __syncthreads();

  // ---- bwd msg MLP on stc ----
  STC_TO_LDS;
  __syncthreads();
  ZERO_ACC;
  MFMA_LAYER(pb.p1, pb.p1 + 16384);
  __syncthreads();
  HIDDEN_TO_LDS(pb.pb1);
  __syncthreads();
  ZERO_ACC;
  MFMA_LAYER(pb.p2, pb.p2 + 16384);
  {
    const float b2a = pb.pb2[w32 + l15];
    const float b2b = pb.pb2[w32 + 16 + l15];
    #pragma unroll
    for (int mt = 0; mt < 4; ++mt)
      #pragma unroll
      for (int nl = 0; nl < 2; ++nl) {
        const int col = w32 + nl * 16 + l15;
        const float bb = nl ? b2b : b2a;
        #pragma unroll
        for (int rg = 0; rg < 4; ++rg) {
          const int row = mt * 16 + q8 * 4 + rg;
          if (row < nrow)
            Mb[(size_t)(row0 + row) * Dd + col] =
                f32_to_bf16_rtn(fmaxf(acc[mt][nl][rg] + bb, 0.f));
        }
      }
  }
}

// ---------------------------------------------------------------------------
// Fused per-round kernel, dual direction (2*782 blocks)
//
// Phase A (line-coalesced): 4 threads per node row; lane q4 of each quad
// owns the q4*16-byte sub-chunk of each 64B line. col[] lists are sorted
// ascending by src so all resident blocks sweep M in the same src order
// (same-XCD L2 keeps the sweep band hot; FETCH 186->157 MB measured R7).
// ---------------------------------------------------------------------------
template <int DO_MSG>
__global__ __launch_bounds__(NT) void aggupdmsg_kernel(
    const ushort* __restrict__ Min_f, const ushort* __restrict__ Min_b,
    const int* __restrict__ rp_f, const int* __restrict__ rp_b,
    const int* __restrict__ col_f, const int* __restrict__ col_b,
    const float* __restrict__ st,
    ushort* __restrict__ RMf, ushort* __restrict__ RMb,
    float* __restrict__ RYf, float* __restrict__ RYb, int rstride,
    DirP pf, DirP pb, int nhalf)
{
  __shared__ __align__(16) ushort Sbuf[2 * TE * LSTR];  // 34.8 KB
  ushort* Sh = Sbuf;
  ushort* Sl = Sbuf + TE * LSTR;
  const int t = threadIdx.x;
  const int dir = blockIdx.x >= nhalf;
  const int row0 = (blockIdx.x - dir * nhalf) * TE;
  const int rem = Nn - row0;
  const int nrow = rem < TE ? rem : TE;
  const DirP P = dir ? pb : pf;
  const ushort* Min = dir ? Min_b : Min_f;
  const int* rp = dir ? rp_b : rp_f;
  const int* col = dir ? col_b : col_f;
  ushort* RoutM = dir ? RMb : RMf;
  float* RoutY = dir ? RYb : RYf;
  const int sink = dir ? 0 : (Nn - 1);

  // ---- phase A: gather-sum of bf16 M rows, f32 accumulate ----
  {
    const int nr = t >> 2;           // tile row, 4 threads per row
    const int q4 = t & 3;            // 16B sub-chunk within each 64B line
    const int qb = (t & 63) & 60;    // quad base lane for shuffles
    // za[2i+h]: cols i*32 + q4*8 + h*4 + (0..3)
    float4 za[8];
    #pragma unroll
    for (int i = 0; i < 8; ++i) za[i] = make_float4(0.f, 0.f, 0.f, 0.f);
    if (nr < nrow) {
      const int gnode = row0 + nr;
      int e = rp[gnode];
      const int ee = rp[gnode + 1];
      const ushort* Mq4 = Min + q4 * 8;   // q4*16 bytes into each row
      for (; e + 3 < ee; e += 4) {   // 16 independent 16B loads in flight
        const int cm = col[e + q4];  // coalesced: quad reads 16B
        const int c0 = __shfl(cm, qb);
        const int c1 = __shfl(cm, qb + 1);
        const int c2 = __shfl(cm, qb + 2);
        const int c3 = __shfl(cm, qb + 3);
        const ushort* r0 = Mq4 + (size_t)c0 * Dd;
        const ushort* r1 = Mq4 + (size_t)c1 * Dd;
        const ushort* r2 = Mq4 + (size_t)c2 * Dd;
        const ushort* r3 = Mq4 + (size_t)c3 * Dd;
        uint4 v0[4], v1[4], v2[4], v3[4];
        #pragma unroll
        for (int i = 0; i < 4; ++i) v0[i] = *(const uint4*)(r0 + i * 32);
        #pragma unroll
        for (int i = 0; i < 4; ++i) v1[i] = *(const uint4*)(r1 + i * 32);
        #pragma unroll
        for (int i = 0; i < 4; ++i) v2[i] = *(const uint4*)(r2 + i * 32);
        #pragma unroll
        for (int i = 0; i < 4; ++i) v3[i] = *(const uint4*)(r3 + i * 32);
        #pragma unroll
        for (int i = 0; i < 4; ++i) {
          acc8(v0[i], za[2 * i], za[2 * i + 1]);
          acc8(v1[i], za[2 * i], za[2 * i + 1]);
          acc8(v2[i], za[2 * i], za[2 * i + 1]);
          acc8(v3[i], za[2 * i], za[2 * i + 1]);
        }
      }
      for (; e < ee; ++e) {
        const ushort* r0 = Mq4 + (size_t)col[e] * Dd;
        #pragma unroll
        for (int i = 0; i < 4; ++i)
          acc8(*(const uint4*)(r0 + i * 32), za[2 * i], za[2 * i + 1]);
      }
    }
    #pragma unroll
    for (int k = 0; k < 8; ++k) {
      ushort4 hv, lv; float rm;
      hv.x = bfsplit(za[k].x, &rm); lv.x = bftrunc(rm);
      hv.y = bfsplit(za[k].y, &rm); lv.y = bftrunc(rm);
      hv.z = bfsplit(za[k].z, &rm); lv.z = bftrunc(rm);
      hv.w = bfsplit(za[k].w, &rm); lv.w = bftrunc(rm);
      const int c4 = (k >> 1) * 32 + q4 * 8 + (k & 1) * 4;
      *(ushort4*)(&Sh[nr * LSTR + c4]) = hv;
      *(ushort4*)(&Sl[nr * LSTR + c4]) = lv;
    }
  }
  __syncthreads();

  MFMA_PRELUDE;

  // ---- phase B: update MLP ----
  ZERO_ACC;
  MFMA_LAYER(P.u1, P.u1 + 16384);
  __syncthreads();
  HIDDEN_TO_LDS(P.ub1);
  __syncthreads();
  ZERO_ACC;
  MFMA_LAYER(P.u2, P.u2 + 16384);

  // y = st + relu(acc + ub2), y[sink-row contribution] zeroed
  {
    const float b2a = P.ub2[w32 + l15];
    const float b2b = P.ub2[w32 + 16 + l15];
    if (DO_MSG) __syncthreads();  // all hidden reads done before overwrite
    #pragma unroll
    for (int mt = 0; mt < 4; ++mt)
      #pragma unroll
      for (int nl = 0; nl < 2; ++nl) {
        const int col = w32 + nl * 16 + l15;
        const float bb = nl ? b2b : b2a;
        #pragma unroll
        for (int rg = 0; rg < 4; ++rg) {
          const int row = mt * 16 + q8 * 4 + rg;
          float v = 0.f;
          if (row < nrow) {
            const int gr = row0 + row;
            v = fmaxf(acc[mt][nl][rg] + bb, 0.f);
            if (gr == sink) v = 0.f;
            v += st[(size_t)gr * Dd + col];
          }
          if (DO_MSG) {
            float rm;
            const ushort hh = bfsplit(v, &rm);
            const int off = row * LSTR + col;
            Sh[off] = hh;
            Sl[off] = bftrunc(rm);
          } else if (row < nrow) {
            RoutY[(size_t)(row0 + row) * rstride + col] = v;
          }
        }
      }
  }

  if (DO_MSG) {
    __syncthreads();
    // ---- phase C: msg MLP on y-tile ----
    ZERO_ACC;
    MFMA_LAYER(P.p1, P.p1 + 16384);
    __syncthreads();
    HIDDEN_TO_LDS(P.pb1);
    __syncthreads();
    ZERO_ACC;
    MFMA_LAYER(P.p2, P.p2 + 16384);

    const float b2a = P.pb2[w32 + l15];
    const float b2b = P.pb2[w32 + 16 + l15];
    #pragma unroll
    for (int mt = 0; mt < 4; ++mt)
      #pragma unroll
      for (int nl = 0; nl < 2; ++nl) {
        const int col = w32 + nl * 16 + l15;
        const float bb = nl ? b2b : b2a;
        #pragma unroll
        for (int rg = 0; rg < 4; ++rg) {
          const int row = mt * 16 + q8 * 4 + rg;
          if (row < nrow)
            RoutM[(size_t)(row0 + row) * Dd + col] =
                f32_to_bf16_rtn(fmaxf(acc[mt][nl][rg] + bb, 0.f));
        }
      }
  }
}

// ---------------------------------------------------------------------------
// Weight packing: matrices -> B-fragment order, split hi/lo.
// ---------------------------------------------------------------------------
struct WPtrs { const float* w[10]; };

__global__ void pack_w_kernel(WPtrs P, ushort* __restrict__ out)
{
  const int id = blockIdx.x * blockDim.x + threadIdx.x;  // 0..16383
  const int mat = blockIdx.y;
  const int j = id & 7;
  const int lane = (id >> 3) & 63;
  const int ch = (id >> 9) & 3;
  const int nt = id >> 11;
  const int k = ch * 32 + (lane >> 4) * 8 + j;
  const int n = nt * 16 + (lane & 15);
  const float x = P.w[mat][k * Dd + n];
  float rm;
  const ushort h = bfsplit(x, &rm);
  out[(size_t)mat * WSLOT + id] = h;
  out[(size_t)mat * WSLOT + 16384 + id] = bftrunc(rm);
}

// ---------------------------------------------------------------------------
// CSR build via 2-level bucket sort (bucket = node >> 8, 196 buckets).
// pairs[dir][i] = (key << 16) | val  (both < 65536 since N = 50000).
// csr_final scatters vals into LDS, sorts each node's segment ascending
// (src-sweep locality for the gather), then streams col[] out coalesced.
// ---------------------------------------------------------------------------
__global__ __launch_bounds__(256) void csr_count(
    const int* __restrict__ src, const int* __restrict__ dst,
    int* __restrict__ bcnt)
{
  const int dirv = blockIdx.y;
  const int* key = dirv ? src : dst;
  __shared__ int h[NBUK];
  const int t = threadIdx.x;
  if (t < NBUK) h[t] = 0;
  __syncthreads();
  const int e0 = blockIdx.x * SCH;
  #pragma unroll
  for (int i = 0; i < SCH / 256; ++i) {
    const int e = e0 + i * 256 + t;
    if (e < Ee) atomicAdd(&h[key[e] >> 8], 1);
  }
  __syncthreads();
  if (t < NBUK && h[t] > 0) atomicAdd(&bcnt[dirv * 256 + t], h[t]);
}

__global__ __launch_bounds__(256) void csr_scan(
    const int* __restrict__ bcnt, int* __restrict__ bbase,
    int* __restrict__ bcur, int* __restrict__ rp)
{
  __shared__ int s[256];
  const int t = threadIdx.x;
  for (int y = 0; y < 2; ++y) {
    const int v = (t < NBUK) ? bcnt[y * 256 + t] : 0;
    s[t] = v;
    __syncthreads();
    for (int off = 1; off < 256; off <<= 1) {
      int x = s[t];
      if (t >= off) x += s[t - off];
      __syncthreads();
      s[t] = x;
      __syncthreads();
    }
    const int excl = s[t] - v;
    if (t < NBUK) { bbase[y * 257 + t] = excl; bcur[y * 256 + t] = excl; }
    if (t == NBUK - 1) bbase[y * 257 + NBUK] = s[t];
    if (t == 0) rp[y * (Nn + 1) + Nn] = Ee;
    __syncthreads();
  }
}

__global__ __launch_bounds__(256) void csr_scatter(
    const int* __restrict__ src, const int* __restrict__ dst,
    int* __restrict__ bcur, uint* __restrict__ pairs)
{
  const int dirv = blockIdx.y;
  const int* key = dirv ? src : dst;
  const int* val = dirv ? dst : src;
  __shared__ int lh[NBUK], gb[NBUK], lc[NBUK];
  const int t = threadIdx.x;
  if (t < NBUK) { lh[t] = 0; lc[t] = 0; }
  __syncthreads();
  const int e0 = blockIdx.x * SCH;
  int ks[SCH / 256], vs[SCH / 256];
  #pragma unroll
  for (int i = 0; i < SCH / 256; ++i) {
    const int e = e0 + i * 256 + t;
    ks[i] = (e < Ee) ? key[e] : -1;
    vs[i] = (e < Ee) ? val[e] : 0;
    if (ks[i] >= 0) atomicAdd(&lh[ks[i] >> 8], 1);
  }
  __syncthreads();
  if (t < NBUK && lh[t] > 0) gb[t] = atomicAdd(&bcur[dirv * 256 + t], lh[t]);
  __syncthreads();
  uint* pd = pairs + (size_t)dirv * Ee;
  #pragma unroll
  for (int i = 0; i < SCH / 256; ++i) {
    if (ks[i] >= 0) {
      const int b = ks[i] >> 8;
      const int r = atomicAdd(&lc[b], 1);
      pd[gb[b] + r] = ((uint)ks[i] << 16) | (uint)vs[i];
    }
  }
}

__global__ __launch_bounds__(256) void csr_final(
    const uint* __restrict__ pairs, const int* __restrict__ bbase,
    int* __restrict__ rp, int* __restrict__ col_f, int* __restrict__ col_b)
{
  const int dirv = blockIdx.y;
  const int b = blockIdx.x;
  const int base = bbase[dirv * 257 + b];
  const int cnt = bbase[dirv * 257 + b + 1] - base;
  const uint* pd = pairs + (size_t)dirv * Ee + base;
  int* colo = dirv ? col_b : col_f;
  __shared__ int h[256];
  __shared__ int s[256];
  __shared__ int cols[FCAP];  // 22 KB
  const int t = threadIdx.x;
  h[t] = 0;
  __syncthreads();
  for (int i = t; i < cnt; i += 256) atomicAdd(&h[(pd[i] >> 16) & 255], 1);
  __syncthreads();
  const int v = h[t];
  s[t] = v;
  __syncthreads();
  for (int off = 1; off < 256; off <<= 1) {
    int x = s[t];
    if (t >= off) x += s[t - off];
    __syncthreads();
    s[t] = x;
    __syncthreads();
  }
  const int excl = s[t] - v;
  const int node = b * 256 + t;
  if (node < Nn) rp[dirv * (Nn + 1) + node] = base + excl;
  h[t] = excl;  // becomes per-node cursor
  __syncthreads();
  if (cnt <= FCAP) {
    // scatter vals into LDS segments
    for (int i = t; i < cnt; i += 256) {
      const uint p = pd[i];
      const int k = (p >> 16) & 255;
      const int r = atomicAdd(&h[k], 1);
      cols[r] = (int)(p & 0xffffu);
    }
    __syncthreads();
    // per-node insertion sort ascending (in LDS)
    if (node < Nn && v > 1) {
      int* seg = cols + excl;
      for (int i = 1; i < v; ++i) {
        const int x = seg[i];
        int j = i - 1;
        while (j >= 0 && seg[j] > x) { seg[j + 1] = seg[j]; --j; }
        seg[j + 1] = x;
      }
    }
    __syncthreads();
    // coalesced stream out
    for (int i = t; i < cnt; i += 256) colo[base + i] = cols[i];
  } else {
    // fallback (statistically unreachable): global scatter + global sort
    for (int i = t; i < cnt; i += 256) {
      const uint p = pd[i];
      const int k = (p >> 16) & 255;
      const int r = atomicAdd(&h[k], 1);
      colo[base + r] = (int)(p & 0xffffu);
    }
    __syncthreads();
    if (node < Nn && v > 1) {
      int* seg = colo + base + excl;
      for (int i = 1; i < v; ++i) {
        const int x = seg[i];
        int j = i - 1;
        while (j >= 0 && seg[j] > x) { seg[j + 1] = seg[j]; --j; }
        seg[j + 1] = x;
      }
    }
  }
}

// ---------------------------------------------------------------------------
extern "C" void kernel_launch(void* const* d_in, const int* in_sizes, int n_in,
                              void* d_out, int out_size, void* d_ws, size_t ws_size,
                              hipStream_t stream)
{
  const float* feat = (const float*)d_in[0];
  const int*   src  = (const int*)d_in[1];
  const int*   dst  = (const int*)d_in[2];

  const float* W[5][4];
  for (int p = 0; p < 5; ++p)
    for (int q = 0; q < 4; ++q)
      W[p][q] = (const float*)d_in[3 + p * 4 + q];

  // workspace: st(f32) + 4x bf16 M arrays + CSR + packed weights
  float* st = (float*)d_ws;                          // [N,D] f32
  ushort* Mp_f = (ushort*)(st + (size_t)Nn * Dd);    // ping fwd [N,D] bf16
  ushort* Mp_b = Mp_f + (size_t)Nn * Dd;             // ping bwd
  ushort* Mq_f = Mp_b + (size_t)Nn * Dd;             // pong fwd
  ushort* Mq_b = Mq_f + (size_t)Nn * Dd;             // pong bwd
  int* ip       = (int*)(Mq_b + (size_t)Nn * Dd);
  int* rp_f     = ip;                 ip += Nn + 1;  // rp_b contiguous after
  int* rp_b     = ip;                 ip += Nn + 1;
  int* col_f    = ip;                 ip += Ee;
  int* col_b    = ip;                 ip += Ee;
  int* bcnt     = ip;                 ip += 2 * 256;
  int* bbase    = ip;                 ip += 2 * 257;
  int* bcur     = ip;                 ip += 2 * 256;
  ushort* Wp = (ushort*)(((uintptr_t)ip + 63) & ~(uintptr_t)63);  // 640 KB
  float* out = (float*)d_out;                        // [N, 2D] f32

  // pairs buffer (6.4 MB) aliases the Mq pong region: CSR build completes
  // (stream-ordered) before round 1 writes Mq.
  uint* pairs = (uint*)Mq_f;

  const int nodeBlocks = (Nn + TE - 1) / TE;    // 782
  const int dualBlocks = 2 * nodeBlocks;        // 1564

  // ---- pack weights ----
  WPtrs wpk;  // slots: 2p = W[p].w1, 2p+1 = W[p].w2
  for (int p = 0; p < 5; ++p) { wpk.w[2 * p] = W[p][0]; wpk.w[2 * p + 1] = W[p][2]; }
  pack_w_kernel<<<dim3(64, 10), NT, 0, stream>>>(wpk, Wp);

  // ---- CSR build via bucket sort ----
  hipMemsetAsync(bcnt, 0, 2 * 256 * sizeof(int), stream);
  csr_count<<<dim3(SB, 2), 256, 0, stream>>>(src, dst, bcnt);
  csr_scan<<<1, 256, 0, stream>>>(bcnt, bbase, bcur, rp_f);
  csr_scatter<<<dim3(SB, 2), 256, 0, stream>>>(src, dst, bcur, pairs);
  csr_final<<<dim3(NBUK, 2), 256, 0, stream>>>(pairs, bbase, rp_f, col_f, col_b);

  #define WS(m) (Wp + (size_t)(m) * WSLOT)
  // fwd: upd = fu (p=2), msg = fp (p=1); bwd: upd = bu (p=4), msg = bp (p=3)
  DirP Pf = { WS(4), WS(5), WS(2), WS(3), W[2][1], W[2][3], W[1][1], W[1][3] };
  DirP Pb = { WS(8), WS(9), WS(6), WS(7), W[4][1], W[4][3], W[3][1], W[3][3] };

  // ---- fused st + round-1 messages ----
  stmsg_kernel<<<nodeBlocks, NT, 0, stream>>>(
      feat, WS(0), WS(1), W[0][1], W[0][3], Pf, Pb, st, Mp_f, Mp_b);

  // ---- round 1: agg+upd+msg, ping -> pong ----
  aggupdmsg_kernel<1><<<dualBlocks, NT, 0, stream>>>(
      Mp_f, Mp_b, rp_f, rp_b, col_f, col_b, st,
      Mq_f, Mq_b, nullptr, nullptr, 0, Pf, Pb, nodeBlocks);

  // ---- round 2: agg+upd+msg, pong -> ping ----
  aggupdmsg_kernel<1><<<dualBlocks, NT, 0, stream>>>(
      Mq_f, Mq_b, rp_f, rp_b, col_f, col_b, st,
      Mp_f, Mp_b, nullptr, nullptr, 0, Pf, Pb, nodeBlocks);

  // ---- round 3 (final): agg+upd, ping -> y into out column-halves ----
  aggupdmsg_kernel<0><<<dualBlocks, NT, 0, stream>>>(
      Mp_f, Mp_b, rp_f, rp_b, col_f, col_b, st,
      nullptr, nullptr, out, out + Dd, 2 * Dd, Pf, Pb, nodeBlocks);

  #undef WS
}

// Round 9
// 544.947 us; speedup vs baseline: 1.3099x; 1.1190x over previous
//
#include <hip/hip_runtime.h>

// Problem constants (reference: N=50000 nodes, E=800000 edges, D=128, K=3)
#define Nn 50000
#define Ee 800000
#define Dd 128
#define Kk 3
#define TE 64    // stmsg rows per block
#define TEA 32   // aggupdmsg rows per block (17.4 KB LDS -> 8 blocks/CU)
#define NT 256   // threads per block (4 waves)

// LDS bf16 tile row stride (ushorts): 128 + 8 pad
#define LSTR 136
// Per-matrix packed-weight slot: hi[16384] + lo[16384] ushorts
#define WSLOT 32768

// Bucket sort CSR build: bucket = node >> 8 (196 buckets for N=50000)
#define NBUK 196
#define SCH 2048                      // edges per sort block
#define SB ((Ee + SCH - 1) / SCH)     // 391 blocks per direction
#define FCAP 5632                     // csr_final LDS capacity (mean 4096, >20 sigma)

typedef short sh8 __attribute__((ext_vector_type(8)));    // 8 bf16 (4 VGPRs)
typedef float f32x4 __attribute__((ext_vector_type(4)));  // MFMA C/D

// Split fp32 into bf16 hi (truncate) + bf16 lo (residual, truncate).
__device__ __forceinline__ ushort bfsplit(float x, float* rem) {
  const unsigned u = __float_as_uint(x);
  *rem = x - __uint_as_float(u & 0xffff0000u);
  return (ushort)(u >> 16);
}
__device__ __forceinline__ ushort bftrunc(float x) {
  return (ushort)(__float_as_uint(x) >> 16);
}
// round-to-nearest f32 -> bf16 (x >= 0, finite)
__device__ __forceinline__ ushort f32_to_bf16_rtn(float x) {
  const unsigned u = __float_as_uint(x);
  return (ushort)((u + 0x7fffu + ((u >> 16) & 1u)) >> 16);
}

// accumulate 8 bf16 packed in one uint4 into two float4 accumulators
__device__ __forceinline__ void acc8(const uint4 v, float4& a0, float4& a1) {
  a0.x += __uint_as_float(v.x << 16);
  a0.y += __uint_as_float(v.x & 0xffff0000u);
  a0.z += __uint_as_float(v.y << 16);
  a0.w += __uint_as_float(v.y & 0xffff0000u);
  a1.x += __uint_as_float(v.z << 16);
  a1.y += __uint_as_float(v.z & 0xffff0000u);
  a1.z += __uint_as_float(v.w << 16);
  a1.w += __uint_as_float(v.w & 0xffff0000u);
}

// (MT*16)x128x128 layer on MFMA 16x16x32_bf16, split-bf16 (3 products).
#define MFMA_LAYER(WH, WL, MT)                                                 \
  {                                                                            \
    _Pragma("unroll")                                                          \
    for (int c = 0; c < 4; ++c) {                                              \
      const sh8 bh0 = *(const sh8*)((WH) + (((nt0    ) * 4 + c) * 64 + lane) * 8); \
      const sh8 bh1 = *(const sh8*)((WH) + (((nt0 + 1) * 4 + c) * 64 + lane) * 8); \
      const sh8 bl0 = *(const sh8*)((WL) + (((nt0    ) * 4 + c) * 64 + lane) * 8); \
      const sh8 bl1 = *(const sh8*)((WL) + (((nt0 + 1) * 4 + c) * 64 + lane) * 8); \
      _Pragma("unroll")                                                        \
      for (int mt = 0; mt < (MT); ++mt) {                                      \
        const int aoff = (mt * 16 + l15) * LSTR + c * 32 + q8 * 8;             \
        const sh8 ah = *(const sh8*)(Sh + aoff);                               \
        const sh8 al = *(const sh8*)(Sl + aoff);                               \
        acc[mt][0] = __builtin_amdgcn_mfma_f32_16x16x32_bf16(ah, bh0, acc[mt][0], 0, 0, 0); \
        acc[mt][1] = __builtin_amdgcn_mfma_f32_16x16x32_bf16(ah, bh1, acc[mt][1], 0, 0, 0); \
        acc[mt][0] = __builtin_amdgcn_mfma_f32_16x16x32_bf16(al, bh0, acc[mt][0], 0, 0, 0); \
        acc[mt][1] = __builtin_amdgcn_mfma_f32_16x16x32_bf16(al, bh1, acc[mt][1], 0, 0, 0); \
        acc[mt][0] = __builtin_amdgcn_mfma_f32_16x16x32_bf16(ah, bl0, acc[mt][0], 0, 0, 0); \
        acc[mt][1] = __builtin_amdgcn_mfma_f32_16x16x32_bf16(ah, bl1, acc[mt][1], 0, 0, 0); \
      }                                                                        \
    }                                                                          \
  }

#define ZERO_ACC(MT)                                             \
  {                                                              \
    _Pragma("unroll")                                            \
    for (int mt = 0; mt < (MT); ++mt)                            \
      _Pragma("unroll")                                          \
      for (int nl = 0; nl < 2; ++nl) {                           \
        acc[mt][nl][0] = 0.f; acc[mt][nl][1] = 0.f;              \
        acc[mt][nl][2] = 0.f; acc[mt][nl][3] = 0.f;              \
      }                                                          \
  }

// hidden = relu(acc + b1) -> split hi/lo back into LDS (C layout -> A layout)
#define HIDDEN_TO_LDS(B1ptr, MT)                                 \
  {                                                              \
    const float b1a = (B1ptr)[w32 + l15];                        \
    const float b1b = (B1ptr)[w32 + 16 + l15];                   \
    _Pragma("unroll")                                            \
    for (int mt = 0; mt < (MT); ++mt)                            \
      _Pragma("unroll")                                          \
      for (int nl = 0; nl < 2; ++nl) {                           \
        const int col = w32 + nl * 16 + l15;                     \
        const float bb = nl ? b1b : b1a;                         \
        _Pragma("unroll")                                        \
        for (int rg = 0; rg < 4; ++rg) {                         \
          const int row = mt * 16 + q8 * 4 + rg;                 \
          const float h = fmaxf(acc[mt][nl][rg] + bb, 0.f);      \
          float rm;                                              \
          const ushort hh = bfsplit(h, &rm);                     \
          const int off = row * LSTR + col;                      \
          Sh[off] = hh;                                          \
          Sl[off] = bftrunc(rm);                                 \
        }                                                        \
      }                                                          \
  }

// stc (C-layout f32, bias included, signed) -> split into LDS A-layout
#define STC_TO_LDS(MT)                                           \
  {                                                              \
    _Pragma("unroll")                                            \
    for (int mt = 0; mt < (MT); ++mt)                            \
      _Pragma("unroll")                                          \
      for (int nl = 0; nl < 2; ++nl) {                           \
        const int col = w32 + nl * 16 + l15;                     \
        _Pragma("unroll")                                        \
        for (int rg = 0; rg < 4; ++rg) {                         \
          const int row = mt * 16 + q8 * 4 + rg;                 \
          float rm;                                              \
          const ushort hh = bfsplit(stc[mt][nl][rg], &rm);       \
          const int off = row * LSTR + col;                      \
          Sh[off] = hh;                                          \
          Sl[off] = bftrunc(rm);                                 \
        }                                                        \
      }                                                          \
  }

// stage rows [row0, row0+nrow) of row-major f32 X (stride Dd) into Sh/Sl split
#define STAGE_ROWS(Xptr)                                                       \
  {                                                                            \
    _Pragma("unroll")                                                          \
    for (int it = 0; it < (TE * 32 / NT); ++it) {                              \
      const int i = t + NT * it;                                               \
      const int r = i >> 5;                                                    \
      const int c4 = (i & 31) << 2;                                            \
      float4 v = make_float4(0.f, 0.f, 0.f, 0.f);                              \
      if (r < nrow) v = *(const float4*)((Xptr) + (size_t)(row0 + r) * Dd + c4); \
      ushort4 hv, lv; float rm;                                                \
      hv.x = bfsplit(v.x, &rm); lv.x = bftrunc(rm);                            \
      hv.y = bfsplit(v.y, &rm); lv.y = bftrunc(rm);                            \
      hv.z = bfsplit(v.z, &rm); lv.z = bftrunc(rm);                            \
      hv.w = bfsplit(v.w, &rm); lv.w = bftrunc(rm);                            \
      *(ushort4*)(&Sh[r * LSTR + c4]) = hv;                                    \
      *(ushort4*)(&Sl[r * LSTR + c4]) = lv;                                    \
    }                                                                          \
  }

#define MFMA_PRELUDE(MT)                                         \
  const int lane = t & 63;                                       \
  const int wave = t >> 6;                                       \
  const int l15 = lane & 15;                                     \
  const int q8 = lane >> 4;                                      \
  const int w32 = wave * 32;                                     \
  const int nt0 = wave * 2;                                      \
  f32x4 acc[MT][2];

// Per-direction parameter pack: packed hi bases (lo = +16384) + biases.
struct DirP {
  const ushort *u1, *u2, *p1, *p2;             // upd w1/w2, msg w1/w2 (packed)
  const float *ub1, *ub2, *pb1, *pb2;
};

// ---------------------------------------------------------------------------
// Fused st + round-1 messages (782 blocks, TE=64)
// ---------------------------------------------------------------------------
__global__ __launch_bounds__(NT) void stmsg_kernel(
    const float* __restrict__ X,
    const ushort* __restrict__ Wn1, const ushort* __restrict__ Wn2,
    const float* __restrict__ Bn1, const float* __restrict__ Bn2,
    DirP pf, DirP pb,
    float* __restrict__ st, ushort* __restrict__ Mf, ushort* __restrict__ Mb)
{
  __shared__ __align__(16) ushort Sbuf[2 * TE * LSTR];  // 34.8 KB
  ushort* Sh = Sbuf;
  ushort* Sl = Sbuf + TE * LSTR;
  const int t = threadIdx.x;
  const int row0 = blockIdx.x * TE;
  const int rem = Nn - row0;
  const int nrow = rem < TE ? rem : TE;

  STAGE_ROWS(X);
  __syncthreads();
  MFMA_PRELUDE(4);

  // ---- nt MLP -> stc ----
  ZERO_ACC(4);
  MFMA_LAYER(Wn1, Wn1 + 16384, 4);
  __syncthreads();
  HIDDEN_TO_LDS(Bn1, 4);
  __syncthreads();
  ZERO_ACC(4);
  MFMA_LAYER(Wn2, Wn2 + 16384, 4);

  float stc[4][2][4];
  {
    const float b2a = Bn2[w32 + l15];
    const float b2b = Bn2[w32 + 16 + l15];
    #pragma unroll
    for (int mt = 0; mt < 4; ++mt)
      #pragma unroll
      for (int nl = 0; nl < 2; ++nl) {
        const int col = w32 + nl * 16 + l15;
        const float bb = nl ? b2b : b2a;
        #pragma unroll
        for (int rg = 0; rg < 4; ++rg) {
          const int row = mt * 16 + q8 * 4 + rg;
          const float v = acc[mt][nl][rg] + bb;
          stc[mt][nl][rg] = v;
          if (row < nrow) st[(size_t)(row0 + row) * Dd + col] = v;
        }
      }
  }
  __syncthreads();  // hidden tile fully consumed

  // ---- fwd msg MLP on stc ----
  STC_TO_LDS(4);
  __syncthreads();
  ZERO_ACC(4);
  MFMA_LAYER(pf.p1, pf.p1 + 16384, 4);
  __syncthreads();
  HIDDEN_TO_LDS(pf.pb1, 4);
  __syncthreads();
  ZERO_ACC(4);
  MFMA_LAYER(pf.p2, pf.p2 + 16384, 4);
  {
    const float b2a = pf.pb2[w32 + l15];
    const float b2b = pf.pb2[w32 + 16 + l15];
    #pragma unroll
    for (int mt = 0; mt < 4; ++mt)
      #pragma unroll
      for (int nl = 0; nl < 2; ++nl) {
        const int col = w32 + nl * 16 + l15;
        const float bb = nl ? b2b : b2a;
        #pragma unroll
        for (int rg = 0; rg < 4; ++rg) {
          const int row = mt * 16 + q8 * 4 + rg;
          if (row < nrow)
            Mf[(size_t)(row0 + row) * Dd + col] =
                f32_to_bf16_rtn(fmaxf(acc[mt][nl][rg] + bb, 0.f));
        }
      }
  }
  __syncthreads();

  // ---- bwd msg MLP on stc ----
  STC_TO_LDS(4);
  __syncthreads();
  ZERO_ACC(4);
  MFMA_LAYER(pb.p1, pb.p1 + 16384, 4);
  __syncthreads();
  HIDDEN_TO_LDS(pb.pb1, 4);
  __syncthreads();
  ZERO_ACC(4);
  MFMA_LAYER(pb.p2, pb.p2 + 16384, 4);
  {
    const float b2a = pb.pb2[w32 + l15];
    const float b2b = pb.pb2[w32 + 16 + l15];
    #pragma unroll
    for (int mt = 0; mt < 4; ++mt)
      #pragma unroll
      for (int nl = 0; nl < 2; ++nl) {
        const int col = w32 + nl * 16 + l15;
        const float bb = nl ? b2b : b2a;
        #pragma unroll
        for (int rg = 0; rg < 4; ++rg) {
          const int row = mt * 16 + q8 * 4 + rg;
          if (row < nrow)
            Mb[(size_t)(row0 + row) * Dd + col] =
                f32_to_bf16_rtn(fmaxf(acc[mt][nl][rg] + bb, 0.f));
        }
      }
  }
}

// ---------------------------------------------------------------------------
// Fused per-round kernel, dual direction (2*1563 blocks, TEA=32 rows)
// 17.4 KB LDS -> 8 blocks/CU (occupancy experiment, R8 theory).
// Phase A: 8 threads per node row; thread o8 owns the contiguous 32 B at
// byte offset o8*32 of each 256 B row (line-perfect). Edge-unrolled x4
// -> 8 outstanding 16 B loads/thread; direct col[] loads (L1 broadcast).
// ---------------------------------------------------------------------------
template <int DO_MSG>
__global__ __launch_bounds__(NT) void aggupdmsg_kernel(
    const ushort* __restrict__ Min_f, const ushort* __restrict__ Min_b,
    const int* __restrict__ rp_f, const int* __restrict__ rp_b,
    const int* __restrict__ col_f, const int* __restrict__ col_b,
    const float* __restrict__ st,
    ushort* __restrict__ RMf, ushort* __restrict__ RMb,
    float* __restrict__ RYf, float* __restrict__ RYb, int rstride,
    DirP pf, DirP pb, int nhalf)
{
  __shared__ __align__(16) ushort Sbuf[2 * TEA * LSTR];  // 17.4 KB
  ushort* Sh = Sbuf;
  ushort* Sl = Sbuf + TEA * LSTR;
  const int t = threadIdx.x;
  const int dir = blockIdx.x >= nhalf;
  const int row0 = (blockIdx.x - dir * nhalf) * TEA;
  const int rem = Nn - row0;
  const int nrow = rem < TEA ? rem : TEA;
  const DirP P = dir ? pb : pf;
  const ushort* Min = dir ? Min_b : Min_f;
  const int* rp = dir ? rp_b : rp_f;
  const int* col = dir ? col_b : col_f;
  ushort* RoutM = dir ? RMb : RMf;
  float* RoutY = dir ? RYb : RYf;
  const int sink = dir ? 0 : (Nn - 1);

  // ---- phase A: gather-sum of bf16 M rows, f32 accumulate ----
  {
    const int nr = t >> 3;           // tile row, 8 threads per row
    const int o8 = t & 7;            // 32B sub-chunk id (cols o8*16..+15)
    float4 za[4];
    #pragma unroll
    for (int i = 0; i < 4; ++i) za[i] = make_float4(0.f, 0.f, 0.f, 0.f);
    if (nr < nrow) {
      const int gnode = row0 + nr;
      int e = rp[gnode];
      const int ee = rp[gnode + 1];
      const ushort* Mo = Min + o8 * 16;   // o8*32 bytes into each row
      for (; e + 3 < ee; e += 4) {   // 8 independent 16B loads in flight
        const int c0 = col[e];
        const int c1 = col[e + 1];
        const int c2 = col[e + 2];
        const int c3 = col[e + 3];
        const ushort* r0 = Mo + (size_t)c0 * Dd;
        const ushort* r1 = Mo + (size_t)c1 * Dd;
        const ushort* r2 = Mo + (size_t)c2 * Dd;
        const ushort* r3 = Mo + (size_t)c3 * Dd;
        uint4 a0 = *(const uint4*)(r0), b0 = *(const uint4*)(r0 + 8);
        uint4 a1 = *(const uint4*)(r1), b1 = *(const uint4*)(r1 + 8);
        uint4 a2 = *(const uint4*)(r2), b2 = *(const uint4*)(r2 + 8);
        uint4 a3 = *(const uint4*)(r3), b3 = *(const uint4*)(r3 + 8);
        acc8(a0, za[0], za[1]); acc8(b0, za[2], za[3]);
        acc8(a1, za[0], za[1]); acc8(b1, za[2], za[3]);
        acc8(a2, za[0], za[1]); acc8(b2, za[2], za[3]);
        acc8(a3, za[0], za[1]); acc8(b3, za[2], za[3]);
      }
      for (; e < ee; ++e) {
        const ushort* r0 = Mo + (size_t)col[e] * Dd;
        acc8(*(const uint4*)(r0), za[0], za[1]);
        acc8(*(const uint4*)(r0 + 8), za[2], za[3]);
      }
    }
    #pragma unroll
    for (int k = 0; k < 4; ++k) {
      ushort4 hv, lv; float rm;
      hv.x = bfsplit(za[k].x, &rm); lv.x = bftrunc(rm);
      hv.y = bfsplit(za[k].y, &rm); lv.y = bftrunc(rm);
      hv.z = bfsplit(za[k].z, &rm); lv.z = bftrunc(rm);
      hv.w = bfsplit(za[k].w, &rm); lv.w = bftrunc(rm);
      const int c4 = o8 * 16 + k * 4;
      *(ushort4*)(&Sh[nr * LSTR + c4]) = hv;
      *(ushort4*)(&Sl[nr * LSTR + c4]) = lv;
    }
  }
  __syncthreads();

  MFMA_PRELUDE(2);

  // ---- phase B: update MLP ----
  ZERO_ACC(2);
  MFMA_LAYER(P.u1, P.u1 + 16384, 2);
  __syncthreads();
  HIDDEN_TO_LDS(P.ub1, 2);
  __syncthreads();
  ZERO_ACC(2);
  MFMA_LAYER(P.u2, P.u2 + 16384, 2);

  // y = st + relu(acc + ub2), y[sink-row contribution] zeroed
  {
    const float b2a = P.ub2[w32 + l15];
    const float b2b = P.ub2[w32 + 16 + l15];
    if (DO_MSG) __syncthreads();  // all hidden reads done before overwrite
    #pragma unroll
    for (int mt = 0; mt < 2; ++mt)
      #pragma unroll
      for (int nl = 0; nl < 2; ++nl) {
        const int col = w32 + nl * 16 + l15;
        const float bb = nl ? b2b : b2a;
        #pragma unroll
        for (int rg = 0; rg < 4; ++rg) {
          const int row = mt * 16 + q8 * 4 + rg;
          float v = 0.f;
          if (row < nrow) {
            const int gr = row0 + row;
            v = fmaxf(acc[mt][nl][rg] + bb, 0.f);
            if (gr == sink) v = 0.f;
            v += st[(size_t)gr * Dd + col];
          }
          if (DO_MSG) {
            float rm;
            const ushort hh = bfsplit(v, &rm);
            const int off = row * LSTR + col;
            Sh[off] = hh;
            Sl[off] = bftrunc(rm);
          } else if (row < nrow) {
            RoutY[(size_t)(row0 + row) * rstride + col] = v;
          }
        }
      }
  }

  if (DO_MSG) {
    __syncthreads();
    // ---- phase C: msg MLP on y-tile ----
    ZERO_ACC(2);
    MFMA_LAYER(P.p1, P.p1 + 16384, 2);
    __syncthreads();
    HIDDEN_TO_LDS(P.pb1, 2);
    __syncthreads();
    ZERO_ACC(2);
    MFMA_LAYER(P.p2, P.p2 + 16384, 2);

    const float b2a = P.pb2[w32 + l15];
    const float b2b = P.pb2[w32 + 16 + l15];
    #pragma unroll
    for (int mt = 0; mt < 2; ++mt)
      #pragma unroll
      for (int nl = 0; nl < 2; ++nl) {
        const int col = w32 + nl * 16 + l15;
        const float bb = nl ? b2b : b2a;
        #pragma unroll
        for (int rg = 0; rg < 4; ++rg) {
          const int row = mt * 16 + q8 * 4 + rg;
          if (row < nrow)
            RoutM[(size_t)(row0 + row) * Dd + col] =
                f32_to_bf16_rtn(fmaxf(acc[mt][nl][rg] + bb, 0.f));
        }
      }
  }
}

// ---------------------------------------------------------------------------
// Weight packing: matrices -> B-fragment order, split hi/lo.
// ---------------------------------------------------------------------------
struct WPtrs { const float* w[10]; };

__global__ void pack_w_kernel(WPtrs P, ushort* __restrict__ out)
{
  const int id = blockIdx.x * blockDim.x + threadIdx.x;  // 0..16383
  const int mat = blockIdx.y;
  const int j = id & 7;
  const int lane = (id >> 3) & 63;
  const int ch = (id >> 9) & 3;
  const int nt = id >> 11;
  const int k = ch * 32 + (lane >> 4) * 8 + j;
  const int n = nt * 16 + (lane & 15);
  const float x = P.w[mat][k * Dd + n];
  float rm;
  const ushort h = bfsplit(x, &rm);
  out[(size_t)mat * WSLOT + id] = h;
  out[(size_t)mat * WSLOT + 16384 + id] = bftrunc(rm);
}

// ---------------------------------------------------------------------------
// CSR build via 2-level bucket sort (bucket = node >> 8, 196 buckets).
// pairs[dir][i] = (key << 16) | val  (both < 65536 since N = 50000).
// csr_final: LDS scatter + cheap 8-band pass (band = src>>13) gives banded
// src order per node (L2 sweep locality) without insertion-sort cost.
// ---------------------------------------------------------------------------
__global__ __launch_bounds__(256) void csr_count(
    const int* __restrict__ src, const int* __restrict__ dst,
    int* __restrict__ bcnt)
{
  const int dirv = blockIdx.y;
  const int* key = dirv ? src : dst;
  __shared__ int h[NBUK];
  const int t = threadIdx.x;
  if (t < NBUK) h[t] = 0;
  __syncthreads();
  const int e0 = blockIdx.x * SCH;
  #pragma unroll
  for (int i = 0; i < SCH / 256; ++i) {
    const int e = e0 + i * 256 + t;
    if (e < Ee) atomicAdd(&h[key[e] >> 8], 1);
  }
  __syncthreads();
  if (t < NBUK && h[t] > 0) atomicAdd(&bcnt[dirv * 256 + t], h[t]);
}

__global__ __launch_bounds__(256) void csr_scan(
    const int* __restrict__ bcnt, int* __restrict__ bbase,
    int* __restrict__ bcur, int* __restrict__ rp)
{
  __shared__ int s[256];
  const int t = threadIdx.x;
  for (int y = 0; y < 2; ++y) {
    const int v = (t < NBUK) ? bcnt[y * 256 + t] : 0;
    s[t] = v;
    __syncthreads();
    for (int off = 1; off < 256; off <<= 1) {
      int x = s[t];
      if (t >= off) x += s[t - off];
      __syncthreads();
      s[t] = x;
      __syncthreads();
    }
    const int excl = s[t] - v;
    if (t < NBUK) { bbase[y * 257 + t] = excl; bcur[y * 256 + t] = excl; }
    if (t == NBUK - 1) bbase[y * 257 + NBUK] = s[t];
    if (t == 0) rp[y * (Nn + 1) + Nn] = Ee;
    __syncthreads();
  }
}

__global__ __launch_bounds__(256) void csr_scatter(
    const int* __restrict__ src, const int* __restrict__ dst,
    int* __restrict__ bcur, uint* __restrict__ pairs)
{
  const int dirv = blockIdx.y;
  const int* key = dirv ? src : dst;
  const int* val = dirv ? dst : src;
  __shared__ int lh[NBUK], gb[NBUK], lc[NBUK];
  const int t = threadIdx.x;
  if (t < NBUK) { lh[t] = 0; lc[t] = 0; }
  __syncthreads();
  const int e0 = blockIdx.x * SCH;
  int ks[SCH / 256], vs[SCH / 256];
  #pragma unroll
  for (int i = 0; i < SCH / 256; ++i) {
    const int e = e0 + i * 256 + t;
    ks[i] = (e < Ee) ? key[e] : -1;
    vs[i] = (e < Ee) ? val[e] : 0;
    if (ks[i] >= 0) atomicAdd(&lh[ks[i] >> 8], 1);
  }
  __syncthreads();
  if (t < NBUK && lh[t] > 0) gb[t] = atomicAdd(&bcur[dirv * 256 + t], lh[t]);
  __syncthreads();
  uint* pd = pairs + (size_t)dirv * Ee;
  #pragma unroll
  for (int i = 0; i < SCH / 256; ++i) {
    if (ks[i] >= 0) {
      const int b = ks[i] >> 8;
      const int r = atomicAdd(&lc[b], 1);
      pd[gb[b] + r] = ((uint)ks[i] << 16) | (uint)vs[i];
    }
  }
}

__global__ __launch_bounds__(256) void csr_final(
    const uint* __restrict__ pairs, const int* __restrict__ bbase,
    int* __restrict__ rp, int* __restrict__ col_f, int* __restrict__ col_b)
{
  const int dirv = blockIdx.y;
  const int b = blockIdx.x;
  const int base = bbase[dirv * 257 + b];
  const int cnt = bbase[dirv * 257 + b + 1] - base;
  const uint* pd = pairs + (size_t)dirv * Ee + base;
  int* colo = dirv ? col_b : col_f;
  __shared__ int h[256];
  __shared__ int s[256];
  __shared__ uint pr[FCAP];   // staged pairs (22.5 KB)
  __shared__ int cols[FCAP];  // banded cols  (22.5 KB)
  const int t = threadIdx.x;
  h[t] = 0;
  __syncthreads();
  const bool fits = (cnt <= FCAP);
  if (fits) {
    for (int i = t; i < cnt; i += 256) {
      const uint p = pd[i];
      pr[i] = p;
      atomicAdd(&h[(p >> 16) & 255], 1);
    }
  } else {
    for (int i = t; i < cnt; i += 256) atomicAdd(&h[(pd[i] >> 16) & 255], 1);
  }
  __syncthreads();
  const int v = h[t];
  s[t] = v;
  __syncthreads();
  for (int off = 1; off < 256; off <<= 1) {
    int x = s[t];
    if (t >= off) x += s[t - off];
    __syncthreads();
    s[t] = x;
    __syncthreads();
  }
  const int excl = s[t] - v;
  const int node = b * 256 + t;
  if (node < Nn) rp[dirv * (Nn + 1) + node] = base + excl;
  h[t] = excl;  // becomes per-node cursor
  __syncthreads();
  if (fits) {
    // 8-band append: per node segment, vals land in ascending src bands
    for (int band = 0; band < 8; ++band) {
      for (int i = t; i < cnt; i += 256) {
        const uint p = pr[i];
        const int vv = (int)(p & 0xffffu);
        if ((vv >> 13) == band) {
          const int k = (p >> 16) & 255;
          const int r = atomicAdd(&h[k], 1);
          cols[r] = vv;
        }
      }
      __syncthreads();
    }
    for (int i = t; i < cnt; i += 256) colo[base + i] = cols[i];
  } else {
    // fallback (statistically unreachable): plain global scatter
    for (int i = t; i < cnt; i += 256) {
      const uint p = pd[i];
      const int k = (p >> 16) & 255;
      const int r = atomicAdd(&h[k], 1);
      colo[base + r] = (int)(p & 0xffffu);
    }
  }
}

// ---------------------------------------------------------------------------
extern "C" void kernel_launch(void* const* d_in, const int* in_sizes, int n_in,
                              void* d_out, int out_size, void* d_ws, size_t ws_size,
                              hipStream_t stream)
{
  const float* feat = (const float*)d_in[0];
  const int*   src  = (const int*)d_in[1];
  const int*   dst  = (const int*)d_in[2];

  const float* W[5][4];
  for (int p = 0; p < 5; ++p)
    for (int q = 0; q < 4; ++q)
      W[p][q] = (const float*)d_in[3 + p * 4 + q];

  // workspace: st(f32) + 4x bf16 M arrays + CSR + packed weights
  float* st = (float*)d_ws;                          // [N,D] f32
  ushort* Mp_f = (ushort*)(st + (size_t)Nn * Dd);    // ping fwd [N,D] bf16
  ushort* Mp_b = Mp_f + (size_t)Nn * Dd;             // ping bwd
  ushort* Mq_f = Mp_b + (size_t)Nn * Dd;             // pong fwd
  ushort* Mq_b = Mq_f + (size_t)Nn * Dd;             // pong bwd
  int* ip       = (int*)(Mq_b + (size_t)Nn * Dd);
  int* rp_f     = ip;                 ip += Nn + 1;  // rp_b contiguous after
  int* rp_b     = ip;                 ip += Nn + 1;
  int* col_f    = ip;                 ip += Ee;
  int* col_b    = ip;                 ip += Ee;
  int* bcnt     = ip;                 ip += 2 * 256;
  int* bbase    = ip;                 ip += 2 * 257;
  int* bcur     = ip;                 ip += 2 * 256;
  ushort* Wp = (ushort*)(((uintptr_t)ip + 63) & ~(uintptr_t)63);  // 640 KB
  float* out = (float*)d_out;                        // [N, 2D] f32

  // pairs buffer (6.4 MB) aliases the Mq pong region: CSR build completes
  // (stream-ordered) before round 1 writes Mq.
  uint* pairs = (uint*)Mq_f;

  const int nodeBlocks = (Nn + TE - 1) / TE;      // 782  (stmsg)
  const int aggBlocks  = (Nn + TEA - 1) / TEA;    // 1563 (agg tiles)
  const int dualBlocks = 2 * aggBlocks;           // 3126

  // ---- pack weights ----
  WPtrs wpk;  // slots: 2p = W[p].w1, 2p+1 = W[p].w2
  for (int p = 0; p < 5; ++p) { wpk.w[2 * p] = W[p][0]; wpk.w[2 * p + 1] = W[p][2]; }
  pack_w_kernel<<<dim3(64, 10), NT, 0, stream>>>(wpk, Wp);

  // ---- CSR build via bucket sort ----
  hipMemsetAsync(bcnt, 0, 2 * 256 * sizeof(int), stream);
  csr_count<<<dim3(SB, 2), 256, 0, stream>>>(src, dst, bcnt);
  csr_scan<<<1, 256, 0, stream>>>(bcnt, bbase, bcur, rp_f);
  csr_scatter<<<dim3(SB, 2), 256, 0, stream>>>(src, dst, bcur, pairs);
  csr_final<<<dim3(NBUK, 2), 256, 0, stream>>>(pairs, bbase, rp_f, col_f, col_b);

  #define WS(m) (Wp + (size_t)(m) * WSLOT)
  // fwd: upd = fu (p=2), msg = fp (p=1); bwd: upd = bu (p=4), msg = bp (p=3)
  DirP Pf = { WS(4), WS(5), WS(2), WS(3), W[2][1], W[2][3], W[1][1], W[1][3] };
  DirP Pb = { WS(8), WS(9), WS(6), WS(7), W[4][1], W[4][3], W[3][1], W[3][3] };

  // ---- fused st + round-1 messages ----
  stmsg_kernel<<<nodeBlocks, NT, 0, stream>>>(
      feat, WS(0), WS(1), W[0][1], W[0][3], Pf, Pb, st, Mp_f, Mp_b);

  // ---- round 1: agg+upd+msg, ping -> pong ----
  aggupdmsg_kernel<1><<<dualBlocks, NT, 0, stream>>>(
      Mp_f, Mp_b, rp_f, rp_b, col_f, col_b, st,
      Mq_f, Mq_b, nullptr, nullptr, 0, Pf, Pb, aggBlocks);

  // ---- round 2: agg+upd+msg, pong -> ping ----
  aggupdmsg_kernel<1><<<dualBlocks, NT, 0, stream>>>(
      Mq_f, Mq_b, rp_f, rp_b, col_f, col_b, st,
      Mp_f, Mp_b, nullptr, nullptr, 0, Pf, Pb, aggBlocks);

  // ---- round 3 (final): agg+upd, ping -> y into out column-halves ----
  aggupdmsg_kernel<0><<<dualBlocks, NT, 0, stream>>>(
      Mp_f, Mp_b, rp_f, rp_b, col_f, col_b, st,
      nullptr, nullptr, out, out + Dd, 2 * Dd, Pf, Pb, aggBlocks);

  #undef WS
}

// Round 10
// 525.183 us; speedup vs baseline: 1.3592x; 1.0376x over previous
//
#include <hip/hip_runtime.h>

// Problem constants (reference: N=50000 nodes, E=800000 edges, D=128, K=3)
#define Nn 50000
#define Ee 800000
#define Dd 128
#define Kk 3
#define TEA 32   // rows per block tile (17.4 KB LDS)
#define NT 256   // threads per block (4 waves)

// LDS bf16 tile row stride (ushorts): 128 + 8 pad
#define LSTR 136
// Per-matrix packed-weight slot: hi[16384] + lo[16384] ushorts
#define WSLOT 32768

// Bucket sort CSR build: bucket = node >> 8 (196 buckets for N=50000)
#define NBUK 196
#define SCH 2048                      // edges per sort block
#define SB ((Ee + SCH - 1) / SCH)     // 391 blocks per direction
#define FCAP 5632                     // csr_final LDS capacity (mean 4096, >20 sigma)

typedef short sh8 __attribute__((ext_vector_type(8)));    // 8 bf16 (4 VGPRs)
typedef float f32x4 __attribute__((ext_vector_type(4)));  // MFMA C/D

// Split fp32 into bf16 hi (truncate) + bf16 lo (residual, truncate).
__device__ __forceinline__ ushort bfsplit(float x, float* rem) {
  const unsigned u = __float_as_uint(x);
  *rem = x - __uint_as_float(u & 0xffff0000u);
  return (ushort)(u >> 16);
}
__device__ __forceinline__ ushort bftrunc(float x) {
  return (ushort)(__float_as_uint(x) >> 16);
}
// round-to-nearest f32 -> bf16 (x >= 0, finite)
__device__ __forceinline__ ushort f32_to_bf16_rtn(float x) {
  const unsigned u = __float_as_uint(x);
  return (ushort)((u + 0x7fffu + ((u >> 16) & 1u)) >> 16);
}

// accumulate 8 bf16 packed in one uint4 into two float4 accumulators
__device__ __forceinline__ void acc8(const uint4 v, float4& a0, float4& a1) {
  a0.x += __uint_as_float(v.x << 16);
  a0.y += __uint_as_float(v.x & 0xffff0000u);
  a0.z += __uint_as_float(v.y << 16);
  a0.w += __uint_as_float(v.y & 0xffff0000u);
  a1.x += __uint_as_float(v.z << 16);
  a1.y += __uint_as_float(v.z & 0xffff0000u);
  a1.z += __uint_as_float(v.w << 16);
  a1.w += __uint_as_float(v.w & 0xffff0000u);
}

// (MT*16)x128x128 layer on MFMA 16x16x32_bf16, split-bf16 (3 products).
#define MFMA_LAYER(WH, WL, MT)                                                 \
  {                                                                            \
    _Pragma("unroll")                                                          \
    for (int c = 0; c < 4; ++c) {                                              \
      const sh8 bh0 = *(const sh8*)((WH) + (((nt0    ) * 4 + c) * 64 + lane) * 8); \
      const sh8 bh1 = *(const sh8*)((WH) + (((nt0 + 1) * 4 + c) * 64 + lane) * 8); \
      const sh8 bl0 = *(const sh8*)((WL) + (((nt0    ) * 4 + c) * 64 + lane) * 8); \
      const sh8 bl1 = *(const sh8*)((WL) + (((nt0 + 1) * 4 + c) * 64 + lane) * 8); \
      _Pragma("unroll")                                                        \
      for (int mt = 0; mt < (MT); ++mt) {                                      \
        const int aoff = (mt * 16 + l15) * LSTR + c * 32 + q8 * 8;             \
        const sh8 ah = *(const sh8*)(Sh + aoff);                               \
        const sh8 al = *(const sh8*)(Sl + aoff);                               \
        acc[mt][0] = __builtin_amdgcn_mfma_f32_16x16x32_bf16(ah, bh0, acc[mt][0], 0, 0, 0); \
        acc[mt][1] = __builtin_amdgcn_mfma_f32_16x16x32_bf16(ah, bh1, acc[mt][1], 0, 0, 0); \
        acc[mt][0] = __builtin_amdgcn_mfma_f32_16x16x32_bf16(al, bh0, acc[mt][0], 0, 0, 0); \
        acc[mt][1] = __builtin_amdgcn_mfma_f32_16x16x32_bf16(al, bh1, acc[mt][1], 0, 0, 0); \
        acc[mt][0] = __builtin_amdgcn_mfma_f32_16x16x32_bf16(ah, bl0, acc[mt][0], 0, 0, 0); \
        acc[mt][1] = __builtin_amdgcn_mfma_f32_16x16x32_bf16(ah, bl1, acc[mt][1], 0, 0, 0); \
      }                                                                        \
    }                                                                          \
  }

#define ZERO_ACC(MT)                                             \
  {                                                              \
    _Pragma("unroll")                                            \
    for (int mt = 0; mt < (MT); ++mt)                            \
      _Pragma("unroll")                                          \
      for (int nl = 0; nl < 2; ++nl) {                           \
        acc[mt][nl][0] = 0.f; acc[mt][nl][1] = 0.f;              \
        acc[mt][nl][2] = 0.f; acc[mt][nl][3] = 0.f;              \
      }                                                          \
  }

// hidden = relu(acc + b1) -> split hi/lo back into LDS (C layout -> A layout)
#define HIDDEN_TO_LDS(B1ptr, MT)                                 \
  {                                                              \
    const float b1a = (B1ptr)[w32 + l15];                        \
    const float b1b = (B1ptr)[w32 + 16 + l15];                   \
    _Pragma("unroll")                                            \
    for (int mt = 0; mt < (MT); ++mt)                            \
      _Pragma("unroll")                                          \
      for (int nl = 0; nl < 2; ++nl) {                           \
        const int col = w32 + nl * 16 + l15;                     \
        const float bb = nl ? b1b : b1a;                         \
        _Pragma("unroll")                                        \
        for (int rg = 0; rg < 4; ++rg) {                         \
          const int row = mt * 16 + q8 * 4 + rg;                 \
          const float h = fmaxf(acc[mt][nl][rg] + bb, 0.f);      \
          float rm;                                              \
          const ushort hh = bfsplit(h, &rm);                     \
          const int off = row * LSTR + col;                      \
          Sh[off] = hh;                                          \
          Sl[off] = bftrunc(rm);                                 \
        }                                                        \
      }                                                          \
  }

// stc (C-layout f32, bias included, signed) -> split into LDS A-layout
#define STC_TO_LDS(MT)                                           \
  {                                                              \
    _Pragma("unroll")                                            \
    for (int mt = 0; mt < (MT); ++mt)                            \
      _Pragma("unroll")                                          \
      for (int nl = 0; nl < 2; ++nl) {                           \
        const int col = w32 + nl * 16 + l15;                     \
        _Pragma("unroll")                                        \
        for (int rg = 0; rg < 4; ++rg) {                         \
          const int row = mt * 16 + q8 * 4 + rg;                 \
          float rm;                                              \
          const ushort hh = bfsplit(stc[mt][nl][rg], &rm);       \
          const int off = row * LSTR + col;                      \
          Sh[off] = hh;                                          \
          Sl[off] = bftrunc(rm);                                 \
        }                                                        \
      }                                                          \
  }

// stage rows [row0, row0+nrow) of row-major f32 X (stride Dd) into Sh/Sl split
#define STAGE_ROWS(Xptr)                                                       \
  {                                                                            \
    _Pragma("unroll")                                                          \
    for (int it = 0; it < (TEA * 32 / NT); ++it) {                             \
      const int i = t + NT * it;                                               \
      const int r = i >> 5;                                                    \
      const int c4 = (i & 31) << 2;                                            \
      float4 v = make_float4(0.f, 0.f, 0.f, 0.f);                              \
      if (r < nrow) v = *(const float4*)((Xptr) + (size_t)(row0 + r) * Dd + c4); \
      ushort4 hv, lv; float rm;                                                \
      hv.x = bfsplit(v.x, &rm); lv.x = bftrunc(rm);                            \
      hv.y = bfsplit(v.y, &rm); lv.y = bftrunc(rm);                            \
      hv.z = bfsplit(v.z, &rm); lv.z = bftrunc(rm);                            \
      hv.w = bfsplit(v.w, &rm); lv.w = bftrunc(rm);                            \
      *(ushort4*)(&Sh[r * LSTR + c4]) = hv;                                    \
      *(ushort4*)(&Sl[r * LSTR + c4]) = lv;                                    \
    }                                                                          \
  }

#define MFMA_PRELUDE(MT)                                         \
  const int lane = t & 63;                                       \
  const int wave = t >> 6;                                       \
  const int l15 = lane & 15;                                     \
  const int q8 = lane >> 4;                                      \
  const int w32 = wave * 32;                                     \
  const int nt0 = wave * 2;                                      \
  f32x4 acc[MT][2];

// Per-direction parameter pack: packed hi bases (lo = +16384) + biases.
struct DirP {
  const ushort *u1, *u2, *p1, *p2;             // upd w1/w2, msg w1/w2 (packed)
  const float *ub1, *ub2, *pb1, *pb2;
};

// ---------------------------------------------------------------------------
// Fused st + round-1 messages (1563 blocks, TEA=32, MT=2)
// ---------------------------------------------------------------------------
__global__ __launch_bounds__(NT) void stmsg_kernel(
    const float* __restrict__ X,
    const ushort* __restrict__ Wn1, const ushort* __restrict__ Wn2,
    const float* __restrict__ Bn1, const float* __restrict__ Bn2,
    DirP pf, DirP pb,
    float* __restrict__ st, ushort* __restrict__ Mf, ushort* __restrict__ Mb)
{
  __shared__ __align__(16) ushort Sbuf[2 * TEA * LSTR];  // 17.4 KB
  ushort* Sh = Sbuf;
  ushort* Sl = Sbuf + TEA * LSTR;
  const int t = threadIdx.x;
  const int row0 = blockIdx.x * TEA;
  const int rem = Nn - row0;
  const int nrow = rem < TEA ? rem : TEA;

  STAGE_ROWS(X);
  __syncthreads();
  MFMA_PRELUDE(2);

  // ---- nt MLP -> stc ----
  ZERO_ACC(2);
  MFMA_LAYER(Wn1, Wn1 + 16384, 2);
  __syncthreads();
  HIDDEN_TO_LDS(Bn1, 2);
  __syncthreads();
  ZERO_ACC(2);
  MFMA_LAYER(Wn2, Wn2 + 16384, 2);

  float stc[2][2][4];
  {
    const float b2a = Bn2[w32 + l15];
    const float b2b = Bn2[w32 + 16 + l15];
    #pragma unroll
    for (int mt = 0; mt < 2; ++mt)
      #pragma unroll
      for (int nl = 0; nl < 2; ++nl) {
        const int col = w32 + nl * 16 + l15;
        const float bb = nl ? b2b : b2a;
        #pragma unroll
        for (int rg = 0; rg < 4; ++rg) {
          const int row = mt * 16 + q8 * 4 + rg;
          const float v = acc[mt][nl][rg] + bb;
          stc[mt][nl][rg] = v;
          if (row < nrow) st[(size_t)(row0 + row) * Dd + col] = v;
        }
      }
  }
  __syncthreads();  // hidden tile fully consumed

  // ---- fwd msg MLP on stc ----
  STC_TO_LDS(2);
  __syncthreads();
  ZERO_ACC(2);
  MFMA_LAYER(pf.p1, pf.p1 + 16384, 2);
  __syncthreads();
  HIDDEN_TO_LDS(pf.pb1, 2);
  __syncthreads();
  ZERO_ACC(2);
  MFMA_LAYER(pf.p2, pf.p2 + 16384, 2);
  {
    const float b2a = pf.pb2[w32 + l15];
    const float b2b = pf.pb2[w32 + 16 + l15];
    #pragma unroll
    for (int mt = 0; mt < 2; ++mt)
      #pragma unroll
      for (int nl = 0; nl < 2; ++nl) {
        const int col = w32 + nl * 16 + l15;
        const float bb = nl ? b2b : b2a;
        #pragma unroll
        for (int rg = 0; rg < 4; ++rg) {
          const int row = mt * 16 + q8 * 4 + rg;
          if (row < nrow)
            Mf[(size_t)(row0 + row) * Dd + col] =
                f32_to_bf16_rtn(fmaxf(acc[mt][nl][rg] + bb, 0.f));
        }
      }
  }
  __syncthreads();

  // ---- bwd msg MLP on stc ----
  STC_TO_LDS(2);
  __syncthreads();
  ZERO_ACC(2);
  MFMA_LAYER(pb.p1, pb.p1 + 16384, 2);
  __syncthreads();
  HIDDEN_TO_LDS(pb.pb1, 2);
  __syncthreads();
  ZERO_ACC(2);
  MFMA_LAYER(pb.p2, pb.p2 + 16384, 2);
  {
    const float b2a = pb.pb2[w32 + l15];
    const float b2b = pb.pb2[w32 + 16 + l15];
    #pragma unroll
    for (int mt = 0; mt < 2; ++mt)
      #pragma unroll
      for (int nl = 0; nl < 2; ++nl) {
        const int col = w32 + nl * 16 + l15;
        const float bb = nl ? b2b : b2a;
        #pragma unroll
        for (int rg = 0; rg < 4; ++rg) {
          const int row = mt * 16 + q8 * 4 + rg;
          if (row < nrow)
            Mb[(size_t)(row0 + row) * Dd + col] =
                f32_to_bf16_rtn(fmaxf(acc[mt][nl][rg] + bb, 0.f));
        }
      }
  }
}

// ---------------------------------------------------------------------------
// Fused per-round kernel, dual direction (2*1563 blocks, TEA=32 rows)
// Phase A: 8 threads per node row; thread o8 owns the contiguous 32 B at
// byte offset o8*32 of each 256 B row (line-perfect). Edge-unrolled x4.
// ---------------------------------------------------------------------------
template <int DO_MSG>
__global__ __launch_bounds__(NT) void aggupdmsg_kernel(
    const ushort* __restrict__ Min_f, const ushort* __restrict__ Min_b,
    const int* __restrict__ rp_f, const int* __restrict__ rp_b,
    const int* __restrict__ col_f, const int* __restrict__ col_b,
    const float* __restrict__ st,
    ushort* __restrict__ RMf, ushort* __restrict__ RMb,
    float* __restrict__ RYf, float* __restrict__ RYb, int rstride,
    DirP pf, DirP pb, int nhalf)
{
  __shared__ __align__(16) ushort Sbuf[2 * TEA * LSTR];  // 17.4 KB
  ushort* Sh = Sbuf;
  ushort* Sl = Sbuf + TEA * LSTR;
  const int t = threadIdx.x;
  const int dir = blockIdx.x >= nhalf;
  const int row0 = (blockIdx.x - dir * nhalf) * TEA;
  const int rem = Nn - row0;
  const int nrow = rem < TEA ? rem : TEA;
  const DirP P = dir ? pb : pf;
  const ushort* Min = dir ? Min_b : Min_f;
  const int* rp = dir ? rp_b : rp_f;
  const int* col = dir ? col_b : col_f;
  ushort* RoutM = dir ? RMb : RMf;
  float* RoutY = dir ? RYb : RYf;
  const int sink = dir ? 0 : (Nn - 1);

  // ---- phase A: gather-sum of bf16 M rows, f32 accumulate ----
  {
    const int nr = t >> 3;           // tile row, 8 threads per row
    const int o8 = t & 7;            // 32B sub-chunk id (cols o8*16..+15)
    float4 za[4];
    #pragma unroll
    for (int i = 0; i < 4; ++i) za[i] = make_float4(0.f, 0.f, 0.f, 0.f);
    if (nr < nrow) {
      const int gnode = row0 + nr;
      int e = rp[gnode];
      const int ee = rp[gnode + 1];
      const ushort* Mo = Min + o8 * 16;   // o8*32 bytes into each row
      for (; e + 3 < ee; e += 4) {   // 8 independent 16B loads in flight
        const int c0 = col[e];
        const int c1 = col[e + 1];
        const int c2 = col[e + 2];
        const int c3 = col[e + 3];
        const ushort* r0 = Mo + (size_t)c0 * Dd;
        const ushort* r1 = Mo + (size_t)c1 * Dd;
        const ushort* r2 = Mo + (size_t)c2 * Dd;
        const ushort* r3 = Mo + (size_t)c3 * Dd;
        uint4 a0 = *(const uint4*)(r0), b0 = *(const uint4*)(r0 + 8);
        uint4 a1 = *(const uint4*)(r1), b1 = *(const uint4*)(r1 + 8);
        uint4 a2 = *(const uint4*)(r2), b2 = *(const uint4*)(r2 + 8);
        uint4 a3 = *(const uint4*)(r3), b3 = *(const uint4*)(r3 + 8);
        acc8(a0, za[0], za[1]); acc8(b0, za[2], za[3]);
        acc8(a1, za[0], za[1]); acc8(b1, za[2], za[3]);
        acc8(a2, za[0], za[1]); acc8(b2, za[2], za[3]);
        acc8(a3, za[0], za[1]); acc8(b3, za[2], za[3]);
      }
      for (; e < ee; ++e) {
        const ushort* r0 = Mo + (size_t)col[e] * Dd;
        acc8(*(const uint4*)(r0), za[0], za[1]);
        acc8(*(const uint4*)(r0 + 8), za[2], za[3]);
      }
    }
    #pragma unroll
    for (int k = 0; k < 4; ++k) {
      ushort4 hv, lv; float rm;
      hv.x = bfsplit(za[k].x, &rm); lv.x = bftrunc(rm);
      hv.y = bfsplit(za[k].y, &rm); lv.y = bftrunc(rm);
      hv.z = bfsplit(za[k].z, &rm); lv.z = bftrunc(rm);
      hv.w = bfsplit(za[k].w, &rm); lv.w = bftrunc(rm);
      const int c4 = o8 * 16 + k * 4;
      *(ushort4*)(&Sh[nr * LSTR + c4]) = hv;
      *(ushort4*)(&Sl[nr * LSTR + c4]) = lv;
    }
  }
  __syncthreads();

  MFMA_PRELUDE(2);

  // ---- phase B: update MLP ----
  ZERO_ACC(2);
  MFMA_LAYER(P.u1, P.u1 + 16384, 2);
  __syncthreads();
  HIDDEN_TO_LDS(P.ub1, 2);
  __syncthreads();
  ZERO_ACC(2);
  MFMA_LAYER(P.u2, P.u2 + 16384, 2);

  // y = st + relu(acc + ub2), y[sink-row contribution] zeroed
  {
    const float b2a = P.ub2[w32 + l15];
    const float b2b = P.ub2[w32 + 16 + l15];
    if (DO_MSG) __syncthreads();  // all hidden reads done before overwrite
    #pragma unroll
    for (int mt = 0; mt < 2; ++mt)
      #pragma unroll
      for (int nl = 0; nl < 2; ++nl) {
        const int col = w32 + nl * 16 + l15;
        const float bb = nl ? b2b : b2a;
        #pragma unroll
        for (int rg = 0; rg < 4; ++rg) {
          const int row = mt * 16 + q8 * 4 + rg;
          float v = 0.f;
          if (row < nrow) {
            const int gr = row0 + row;
            v = fmaxf(acc[mt][nl][rg] + bb, 0.f);
            if (gr == sink) v = 0.f;
            v += st[(size_t)gr * Dd + col];
          }
          if (DO_MSG) {
            float rm;
            const ushort hh = bfsplit(v, &rm);
            const int off = row * LSTR + col;
            Sh[off] = hh;
            Sl[off] = bftrunc(rm);
          } else if (row < nrow) {
            RoutY[(size_t)(row0 + row) * rstride + col] = v;
          }
        }
      }
  }

  if (DO_MSG) {
    __syncthreads();
    // ---- phase C: msg MLP on y-tile ----
    ZERO_ACC(2);
    MFMA_LAYER(P.p1, P.p1 + 16384, 2);
    __syncthreads();
    HIDDEN_TO_LDS(P.pb1, 2);
    __syncthreads();
    ZERO_ACC(2);
    MFMA_LAYER(P.p2, P.p2 + 16384, 2);

    const float b2a = P.pb2[w32 + l15];
    const float b2b = P.pb2[w32 + 16 + l15];
    #pragma unroll
    for (int mt = 0; mt < 2; ++mt)
      #pragma unroll
      for (int nl = 0; nl < 2; ++nl) {
        const int col = w32 + nl * 16 + l15;
        const float bb = nl ? b2b : b2a;
        #pragma unroll
        for (int rg = 0; rg < 4; ++rg) {
          const int row = mt * 16 + q8 * 4 + rg;
          if (row < nrow)
            RoutM[(size_t)(row0 + row) * Dd + col] =
                f32_to_bf16_rtn(fmaxf(acc[mt][nl][rg] + bb, 0.f));
        }
      }
  }
}

// ---------------------------------------------------------------------------
// CSR build via 2-level bucket sort (bucket = node >> 8, 196 buckets).
// pairs[dir][i] = (key << 16) | val  (both < 65536 since N = 50000).
// ---------------------------------------------------------------------------
struct WPtrs { const float* w[10]; };

__global__ __launch_bounds__(256) void csr_count(
    const int* __restrict__ src, const int* __restrict__ dst,
    int* __restrict__ bcnt)
{
  const int dirv = blockIdx.y;
  const int* key = dirv ? src : dst;
  __shared__ int h[NBUK];
  const int t = threadIdx.x;
  if (t < NBUK) h[t] = 0;
  __syncthreads();
  const int e0 = blockIdx.x * SCH;
  #pragma unroll
  for (int i = 0; i < SCH / 256; ++i) {
    const int e = e0 + i * 256 + t;
    if (e < Ee) atomicAdd(&h[key[e] >> 8], 1);
  }
  __syncthreads();
  if (t < NBUK && h[t] > 0) atomicAdd(&bcnt[dirv * 256 + t], h[t]);
}

// block 0: bucket scan; blocks 1..640: weight packing (independent work,
// fused to hide the serial scan behind the pack kernel's runtime).
__global__ __launch_bounds__(256) void csr_scan_pack(
    const int* __restrict__ bcnt, int* __restrict__ bbase,
    int* __restrict__ bcur, int* __restrict__ rp,
    WPtrs P, ushort* __restrict__ out)
{
  const int t = threadIdx.x;
  if (blockIdx.x == 0) {
    __shared__ int s[256];
    for (int y = 0; y < 2; ++y) {
      const int v = (t < NBUK) ? bcnt[y * 256 + t] : 0;
      s[t] = v;
      __syncthreads();
      for (int off = 1; off < 256; off <<= 1) {
        int x = s[t];
        if (t >= off) x += s[t - off];
        __syncthreads();
        s[t] = x;
        __syncthreads();
      }
      const int excl = s[t] - v;
      if (t < NBUK) { bbase[y * 257 + t] = excl; bcur[y * 256 + t] = excl; }
      if (t == NBUK - 1) bbase[y * 257 + NBUK] = s[t];
      if (t == 0) rp[y * (Nn + 1) + Nn] = Ee;
      __syncthreads();
    }
  } else {
    const int work = (blockIdx.x - 1) * 256 + t;  // 0..163839
    const int mat = work >> 14;                   // /16384
    const int id = work & 16383;
    const int j = id & 7;
    const int lane = (id >> 3) & 63;
    const int ch = (id >> 9) & 3;
    const int nt = id >> 11;
    const int k = ch * 32 + (lane >> 4) * 8 + j;
    const int n = nt * 16 + (lane & 15);
    const float x = P.w[mat][k * Dd + n];
    float rm;
    const ushort h = bfsplit(x, &rm);
    out[(size_t)mat * WSLOT + id] = h;
    out[(size_t)mat * WSLOT + 16384 + id] = bftrunc(rm);
  }
}

__global__ __launch_bounds__(256) void csr_scatter(
    const int* __restrict__ src, const int* __restrict__ dst,
    int* __restrict__ bcur, uint* __restrict__ pairs)
{
  const int dirv = blockIdx.y;
  const int* key = dirv ? src : dst;
  const int* val = dirv ? dst : src;
  __shared__ int lh[NBUK], gb[NBUK], lc[NBUK];
  const int t = threadIdx.x;
  if (t < NBUK) { lh[t] = 0; lc[t] = 0; }
  __syncthreads();
  const int e0 = blockIdx.x * SCH;
  int ks[SCH / 256], vs[SCH / 256];
  #pragma unroll
  for (int i = 0; i < SCH / 256; ++i) {
    const int e = e0 + i * 256 + t;
    ks[i] = (e < Ee) ? key[e] : -1;
    vs[i] = (e < Ee) ? val[e] : 0;
    if (ks[i] >= 0) atomicAdd(&lh[ks[i] >> 8], 1);
  }
  __syncthreads();
  if (t < NBUK && lh[t] > 0) gb[t] = atomicAdd(&bcur[dirv * 256 + t], lh[t]);
  __syncthreads();
  uint* pd = pairs + (size_t)dirv * Ee;
  #pragma unroll
  for (int i = 0; i < SCH / 256; ++i) {
    if (ks[i] >= 0) {
      const int b = ks[i] >> 8;
      const int r = atomicAdd(&lc[b], 1);
      pd[gb[b] + r] = ((uint)ks[i] << 16) | (uint)vs[i];
    }
  }
}

// LDS pair staging + 8-band src-ordered emit (band = src>>13). Writes colo
// directly to global (4B scatter within a 16KB L2-hot window).
__global__ __launch_bounds__(256) void csr_final(
    const uint* __restrict__ pairs, const int* __restrict__ bbase,
    int* __restrict__ rp, int* __restrict__ col_f, int* __restrict__ col_b)
{
  const int dirv = blockIdx.y;
  const int b = blockIdx.x;
  const int base = bbase[dirv * 257 + b];
  const int cnt = bbase[dirv * 257 + b + 1] - base;
  const uint* pd = pairs + (size_t)dirv * Ee + base;
  int* colo = dirv ? col_b : col_f;
  __shared__ int h[256];
  __shared__ int s[256];
  __shared__ uint pr[FCAP];   // staged pairs (22.5 KB)
  const int t = threadIdx.x;
  h[t] = 0;
  __syncthreads();
  const bool fits = (cnt <= FCAP);
  if (fits) {
    for (int i = t; i < cnt; i += 256) {
      const uint p = pd[i];
      pr[i] = p;
      atomicAdd(&h[(p >> 16) & 255], 1);
    }
  } else {
    for (int i = t; i < cnt; i += 256) atomicAdd(&h[(pd[i] >> 16) & 255], 1);
  }
  __syncthreads();
  const int v = h[t];
  s[t] = v;
  __syncthreads();
  for (int off = 1; off < 256; off <<= 1) {
    int x = s[t];
    if (t >= off) x += s[t - off];
    __syncthreads();
    s[t] = x;
    __syncthreads();
  }
  const int excl = s[t] - v;
  const int node = b * 256 + t;
  if (node < Nn) rp[dirv * (Nn + 1) + node] = base + excl;
  h[t] = excl;  // becomes per-node cursor
  __syncthreads();
  if (fits) {
    for (int band = 0; band < 8; ++band) {
      for (int i = t; i < cnt; i += 256) {
        const uint p = pr[i];
        const int vv = (int)(p & 0xffffu);
        if ((vv >> 13) == band) {
          const int k = (p >> 16) & 255;
          const int r = atomicAdd(&h[k], 1);
          colo[base + r] = vv;
        }
      }
      __syncthreads();
    }
  } else {
    // fallback (statistically unreachable): plain scatter
    for (int i = t; i < cnt; i += 256) {
      const uint p = pd[i];
      const int k = (p >> 16) & 255;
      const int r = atomicAdd(&h[k], 1);
      colo[base + r] = (int)(p & 0xffffu);
    }
  }
}

// ---------------------------------------------------------------------------
extern "C" void kernel_launch(void* const* d_in, const int* in_sizes, int n_in,
                              void* d_out, int out_size, void* d_ws, size_t ws_size,
                              hipStream_t stream)
{
  const float* feat = (const float*)d_in[0];
  const int*   src  = (const int*)d_in[1];
  const int*   dst  = (const int*)d_in[2];

  const float* W[5][4];
  for (int p = 0; p < 5; ++p)
    for (int q = 0; q < 4; ++q)
      W[p][q] = (const float*)d_in[3 + p * 4 + q];

  // workspace: st(f32) + 4x bf16 M arrays + CSR + packed weights
  float* st = (float*)d_ws;                          // [N,D] f32
  ushort* Mp_f = (ushort*)(st + (size_t)Nn * Dd);    // ping fwd [N,D] bf16
  ushort* Mp_b = Mp_f + (size_t)Nn * Dd;             // ping bwd
  ushort* Mq_f = Mp_b + (size_t)Nn * Dd;             // pong fwd
  ushort* Mq_b = Mq_f + (size_t)Nn * Dd;             // pong bwd
  int* ip       = (int*)(Mq_b + (size_t)Nn * Dd);
  int* rp_f     = ip;                 ip += Nn + 1;  // rp_b contiguous after
  int* rp_b     = ip;                 ip += Nn + 1;
  int* col_f    = ip;                 ip += Ee;
  int* col_b    = ip;                 ip += Ee;
  int* bcnt     = ip;                 ip += 2 * 256;
  int* bbase    = ip;                 ip += 2 * 257;
  int* bcur     = ip;                 ip += 2 * 256;
  ushort* Wp = (ushort*)(((uintptr_t)ip + 63) & ~(uintptr_t)63);  // 640 KB
  float* out = (float*)d_out;                        // [N, 2D] f32

  // pairs buffer (6.4 MB) aliases the Mq pong region: CSR build completes
  // (stream-ordered) before round 1 writes Mq.
  uint* pairs = (uint*)Mq_f;

  const int aggBlocks  = (Nn + TEA - 1) / TEA;    // 1563 tiles
  const int dualBlocks = 2 * aggBlocks;           // 3126

  // ---- CSR build via bucket sort (+ fused weight packing) ----
  WPtrs wpk;  // slots: 2p = W[p].w1, 2p+1 = W[p].w2
  for (int p = 0; p < 5; ++p) { wpk.w[2 * p] = W[p][0]; wpk.w[2 * p + 1] = W[p][2]; }

  hipMemsetAsync(bcnt, 0, 2 * 256 * sizeof(int), stream);
  csr_count<<<dim3(SB, 2), 256, 0, stream>>>(src, dst, bcnt);
  csr_scan_pack<<<641, 256, 0, stream>>>(bcnt, bbase, bcur, rp_f, wpk, Wp);
  csr_scatter<<<dim3(SB, 2), 256, 0, stream>>>(src, dst, bcur, pairs);
  csr_final<<<dim3(NBUK, 2), 256, 0, stream>>>(pairs, bbase, rp_f, col_f, col_b);

  #define WS(m) (Wp + (size_t)(m) * WSLOT)
  // fwd: upd = fu (p=2), msg = fp (p=1); bwd: upd = bu (p=4), msg = bp (p=3)
  DirP Pf = { WS(4), WS(5), WS(2), WS(3), W[2][1], W[2][3], W[1][1], W[1][3] };
  DirP Pb = { WS(8), WS(9), WS(6), WS(7), W[4][1], W[4][3], W[3][1], W[3][3] };

  // ---- fused st + round-1 messages ----
  stmsg_kernel<<<aggBlocks, NT, 0, stream>>>(
      feat, WS(0), WS(1), W[0][1], W[0][3], Pf, Pb, st, Mp_f, Mp_b);

  // ---- round 1: agg+upd+msg, ping -> pong ----
  aggupdmsg_kernel<1><<<dualBlocks, NT, 0, stream>>>(
      Mp_f, Mp_b, rp_f, rp_b, col_f, col_b, st,
      Mq_f, Mq_b, nullptr, nullptr, 0, Pf, Pb, aggBlocks);

  // ---- round 2: agg+upd+msg, pong -> ping ----
  aggupdmsg_kernel<1><<<dualBlocks, NT, 0, stream>>>(
      Mq_f, Mq_b, rp_f, rp_b, col_f, col_b, st,
      Mp_f, Mp_b, nullptr, nullptr, 0, Pf, Pb, aggBlocks);

  // ---- round 3 (final): agg+upd, ping -> y into out column-halves ----
  aggupdmsg_kernel<0><<<dualBlocks, NT, 0, stream>>>(
      Mp_f, Mp_b, rp_f, rp_b, col_f, col_b, st,
      nullptr, nullptr, out, out + Dd, 2 * Dd, Pf, Pb, aggBlocks);

  #undef WS
}

// Round 12
// 523.382 us; speedup vs baseline: 1.3639x; 1.0034x over previous
//
#include <hip/hip_runtime.h>

// Problem constants (reference: N=50000 nodes, E=800000 edges, D=128, K=3)
#define Nn 50000
#define Ee 800000
#define Dd 128
#define Kk 3
#define TEA 32   // rows per block tile (17.4 KB LDS)
#define NT 256   // threads per block (4 waves)

// LDS bf16 tile row stride (ushorts): 128 + 8 pad
#define LSTR 136
// Per-matrix packed-weight slot: hi[16384] + lo[16384] ushorts
#define WSLOT 32768

// Bucket sort CSR build: bucket = node >> 8 (196 buckets for N=50000)
#define NBUK 196
#define SCH 2048                      // edges per sort block
#define SB ((Ee + SCH - 1) / SCH)     // 391 blocks per direction
#define FCAP 5632                     // csr_final LDS staging capacity

typedef short sh8 __attribute__((ext_vector_type(8)));    // 8 bf16 (4 VGPRs)
typedef float f32x4 __attribute__((ext_vector_type(4)));  // MFMA C/D

// Split fp32 into bf16 hi (truncate) + bf16 lo (residual, truncate).
__device__ __forceinline__ ushort bfsplit(float x, float* rem) {
  const unsigned u = __float_as_uint(x);
  *rem = x - __uint_as_float(u & 0xffff0000u);
  return (ushort)(u >> 16);
}
__device__ __forceinline__ ushort bftrunc(float x) {
  return (ushort)(__float_as_uint(x) >> 16);
}
// round-to-nearest f32 -> bf16 (x >= 0, finite)
__device__ __forceinline__ ushort f32_to_bf16_rtn(float x) {
  const unsigned u = __float_as_uint(x);
  return (ushort)((u + 0x7fffu + ((u >> 16) & 1u)) >> 16);
}

// accumulate 8 bf16 packed in one uint4 into two float4 accumulators
__device__ __forceinline__ void acc8(const uint4 v, float4& a0, float4& a1) {
  a0.x += __uint_as_float(v.x << 16);
  a0.y += __uint_as_float(v.x & 0xffff0000u);
  a0.z += __uint_as_float(v.y << 16);
  a0.w += __uint_as_float(v.y & 0xffff0000u);
  a1.x += __uint_as_float(v.z << 16);
  a1.y += __uint_as_float(v.z & 0xffff0000u);
  a1.z += __uint_as_float(v.w << 16);
  a1.w += __uint_as_float(v.w & 0xffff0000u);
}

// (MT*16)x128x128 layer on MFMA 16x16x32_bf16, split-bf16 (3 products).
#define MFMA_LAYER(WH, WL, MT)                                                 \
  {                                                                            \
    _Pragma("unroll")                                                          \
    for (int c = 0; c < 4; ++c) {                                              \
      const sh8 bh0 = *(const sh8*)((WH) + (((nt0    ) * 4 + c) * 64 + lane) * 8); \
      const sh8 bh1 = *(const sh8*)((WH) + (((nt0 + 1) * 4 + c) * 64 + lane) * 8); \
      const sh8 bl0 = *(const sh8*)((WL) + (((nt0    ) * 4 + c) * 64 + lane) * 8); \
      const sh8 bl1 = *(const sh8*)((WL) + (((nt0 + 1) * 4 + c) * 64 + lane) * 8); \
      _Pragma("unroll")                                                        \
      for (int mt = 0; mt < (MT); ++mt) {                                      \
        const int aoff = (mt * 16 + l15) * LSTR + c * 32 + q8 * 8;             \
        const sh8 ah = *(const sh8*)(Sh + aoff);                               \
        const sh8 al = *(const sh8*)(Sl + aoff);                               \
        acc[mt][0] = __builtin_amdgcn_mfma_f32_16x16x32_bf16(ah, bh0, acc[mt][0], 0, 0, 0); \
        acc[mt][1] = __builtin_amdgcn_mfma_f32_16x16x32_bf16(ah, bh1, acc[mt][1], 0, 0, 0); \
        acc[mt][0] = __builtin_amdgcn_mfma_f32_16x16x32_bf16(al, bh0, acc[mt][0], 0, 0, 0); \
        acc[mt][1] = __builtin_amdgcn_mfma_f32_16x16x32_bf16(al, bh1, acc[mt][1], 0, 0, 0); \
        acc[mt][0] = __builtin_amdgcn_mfma_f32_16x16x32_bf16(ah, bl0, acc[mt][0], 0, 0, 0); \
        acc[mt][1] = __builtin_amdgcn_mfma_f32_16x16x32_bf16(ah, bl1, acc[mt][1], 0, 0, 0); \
      }                                                                        \
    }                                                                          \
  }

#define ZERO_ACC(MT)                                             \
  {                                                              \
    _Pragma("unroll")                                            \
    for (int mt = 0; mt < (MT); ++mt)                            \
      _Pragma("unroll")                                          \
      for (int nl = 0; nl < 2; ++nl) {                           \
        acc[mt][nl][0] = 0.f; acc[mt][nl][1] = 0.f;              \
        acc[mt][nl][2] = 0.f; acc[mt][nl][3] = 0.f;              \
      }                                                          \
  }

// hidden = relu(acc + b1) -> split hi/lo back into LDS (C layout -> A layout)
#define HIDDEN_TO_LDS(B1ptr, MT)                                 \
  {                                                              \
    const float b1a = (B1ptr)[w32 + l15];                        \
    const float b1b = (B1ptr)[w32 + 16 + l15];                   \
    _Pragma("unroll")                                            \
    for (int mt = 0; mt < (MT); ++mt)                            \
      _Pragma("unroll")                                          \
      for (int nl = 0; nl < 2; ++nl) {                           \
        const int col = w32 + nl * 16 + l15;                     \
        const float bb = nl ? b1b : b1a;                         \
        _Pragma("unroll")                                        \
        for (int rg = 0; rg < 4; ++rg) {                         \
          const int row = mt * 16 + q8 * 4 + rg;                 \
          const float h = fmaxf(acc[mt][nl][rg] + bb, 0.f);      \
          float rm;                                              \
          const ushort hh = bfsplit(h, &rm);                     \
          const int off = row * LSTR + col;                      \
          Sh[off] = hh;                                          \
          Sl[off] = bftrunc(rm);                                 \
        }                                                        \
      }                                                          \
  }

// stc (C-layout f32, bias included, signed) -> split into LDS A-layout
#define STC_TO_LDS(MT)                                           \
  {                                                              \
    _Pragma("unroll")                                            \
    for (int mt = 0; mt < (MT); ++mt)                            \
      _Pragma("unroll")                                          \
      for (int nl = 0; nl < 2; ++nl) {                           \
        const int col = w32 + nl * 16 + l15;                     \
        _Pragma("unroll")                                        \
        for (int rg = 0; rg < 4; ++rg) {                         \
          const int row = mt * 16 + q8 * 4 + rg;                 \
          float rm;                                              \
          const ushort hh = bfsplit(stc[mt][nl][rg], &rm);       \
          const int off = row * LSTR + col;                      \
          Sh[off] = hh;                                          \
          Sl[off] = bftrunc(rm);                                 \
        }                                                        \
      }                                                          \
  }

// stage rows [row0, row0+nrow) of row-major f32 X (stride Dd) into Sh/Sl split
#define STAGE_ROWS(Xptr)                                                       \
  {                                                                            \
    _Pragma("unroll")                                                          \
    for (int it = 0; it < (TEA * 32 / NT); ++it) {                             \
      const int i = t + NT * it;                                               \
      const int r = i >> 5;                                                    \
      const int c4 = (i & 31) << 2;                                            \
      float4 v = make_float4(0.f, 0.f, 0.f, 0.f);                              \
      if (r < nrow) v = *(const float4*)((Xptr) + (size_t)(row0 + r) * Dd + c4); \
      ushort4 hv, lv; float rm;                                                \
      hv.x = bfsplit(v.x, &rm); lv.x = bftrunc(rm);                            \
      hv.y = bfsplit(v.y, &rm); lv.y = bftrunc(rm);                            \
      hv.z = bfsplit(v.z, &rm); lv.z = bftrunc(rm);                            \
      hv.w = bfsplit(v.w, &rm); lv.w = bftrunc(rm);                            \
      *(ushort4*)(&Sh[r * LSTR + c4]) = hv;                                    \
      *(ushort4*)(&Sl[r * LSTR + c4]) = lv;                                    \
    }                                                                          \
  }

#define MFMA_PRELUDE(MT)                                         \
  const int lane = t & 63;                                       \
  const int wave = t >> 6;                                       \
  const int l15 = lane & 15;                                     \
  const int q8 = lane >> 4;                                      \
  const int w32 = wave * 32;                                     \
  const int nt0 = wave * 2;                                      \
  f32x4 acc[MT][2];

// Per-direction parameter pack: packed hi bases (lo = +16384) + biases.
struct DirP {
  const ushort *u1, *u2, *p1, *p2;             // upd w1/w2, msg w1/w2 (packed)
  const float *ub1, *ub2, *pb1, *pb2;
};

struct WPtrs { const float* w[10]; };

// ---------------------------------------------------------------------------
// CSR build via 2-level bucket sort (bucket = node >> 8, 196 buckets).
// pairs[dir][i] = (key << 16) | val  (both < 65536 since N = 50000).
// ---------------------------------------------------------------------------
__global__ __launch_bounds__(256) void csr_count(
    const int* __restrict__ src, const int* __restrict__ dst,
    int* __restrict__ bcnt)
{
  const int dirv = blockIdx.y;
  const int* key = dirv ? src : dst;
  __shared__ int h[NBUK];
  const int t = threadIdx.x;
  if (t < NBUK) h[t] = 0;
  __syncthreads();
  const int e0 = blockIdx.x * SCH;
  #pragma unroll
  for (int i = 0; i < SCH / 256; ++i) {
    const int e = e0 + i * 256 + t;
    if (e < Ee) atomicAdd(&h[key[e] >> 8], 1);
  }
  __syncthreads();
  if (t < NBUK && h[t] > 0) atomicAdd(&bcnt[dirv * 256 + t], h[t]);
}

// block 0: bucket scan; blocks 1..640: weight packing (independent work,
// fused to hide the serial scan behind the pack kernel's runtime).
__global__ __launch_bounds__(256) void csr_scan_pack(
    const int* __restrict__ bcnt, int* __restrict__ bbase,
    int* __restrict__ bcur, int* __restrict__ rp,
    WPtrs P, ushort* __restrict__ out)
{
  const int t = threadIdx.x;
  if (blockIdx.x == 0) {
    __shared__ int s[256];
    for (int y = 0; y < 2; ++y) {
      const int v = (t < NBUK) ? bcnt[y * 256 + t] : 0;
      s[t] = v;
      __syncthreads();
      for (int off = 1; off < 256; off <<= 1) {
        int x = s[t];
        if (t >= off) x += s[t - off];
        __syncthreads();
        s[t] = x;
        __syncthreads();
      }
      const int excl = s[t] - v;
      if (t < NBUK) { bbase[y * 257 + t] = excl; bcur[y * 256 + t] = excl; }
      if (t == NBUK - 1) bbase[y * 257 + NBUK] = s[t];
      if (t == 0) rp[y * (Nn + 1) + Nn] = Ee;
      __syncthreads();
    }
  } else {
    const int work = (blockIdx.x - 1) * 256 + t;  // 0..163839
    const int mat = work >> 14;                   // /16384
    const int id = work & 16383;
    const int j = id & 7;
    const int lane = (id >> 3) & 63;
    const int ch = (id >> 9) & 3;
    const int nt = id >> 11;
    const int k = ch * 32 + (lane >> 4) * 8 + j;
    const int n = nt * 16 + (lane & 15);
    const float x = P.w[mat][k * Dd + n];
    float rm;
    const ushort h = bfsplit(x, &rm);
    out[(size_t)mat * WSLOT + id] = h;
    out[(size_t)mat * WSLOT + 16384 + id] = bftrunc(rm);
  }
}

// ---------------------------------------------------------------------------
// Fused kernel: blocks [0, 2*SB) run the R10 csr_scatter body (compact
// append at pre-scanned bases); blocks [2*SB, 2*SB + nodeTiles) run the R10
// stmsg body. Independent work shares one dispatch so the scatter's ~15us
// hides under stmsg instead of serializing.
// ---------------------------------------------------------------------------
__global__ __launch_bounds__(NT) void scatter_stmsg_kernel(
    const int* __restrict__ src, const int* __restrict__ dst,
    int* __restrict__ bcur, uint* __restrict__ pairs,
    const float* __restrict__ X,
    const ushort* __restrict__ Wn1, const ushort* __restrict__ Wn2,
    const float* __restrict__ Bn1, const float* __restrict__ Bn2,
    DirP pf, DirP pb,
    float* __restrict__ st, ushort* __restrict__ Mf, ushort* __restrict__ Mb,
    int nScatter)
{
  __shared__ __align__(16) ushort Sbuf[2 * TEA * LSTR];  // 17.4 KB
  const int t = threadIdx.x;

  if ((int)blockIdx.x < nScatter) {
    // ---- scatter branch (R10 csr_scatter body) ----
    int* lh = (int*)Sbuf;
    int* gb = lh + 256;
    int* lc = gb + 256;
    const int dirv = (int)blockIdx.x >= SB;
    const int sb = blockIdx.x - dirv * SB;
    const int* key = dirv ? src : dst;
    const int* val = dirv ? dst : src;
    if (t < NBUK) { lh[t] = 0; lc[t] = 0; }
    __syncthreads();
    const int e0 = sb * SCH;
    int ks[SCH / 256], vs[SCH / 256];
    #pragma unroll
    for (int i = 0; i < SCH / 256; ++i) {
      const int e = e0 + i * 256 + t;
      ks[i] = (e < Ee) ? key[e] : -1;
      vs[i] = (e < Ee) ? val[e] : 0;
      if (ks[i] >= 0) atomicAdd(&lh[ks[i] >> 8], 1);
    }
    __syncthreads();
    if (t < NBUK && lh[t] > 0) gb[t] = atomicAdd(&bcur[dirv * 256 + t], lh[t]);
    __syncthreads();
    uint* pd = pairs + (size_t)dirv * Ee;
    #pragma unroll
    for (int i = 0; i < SCH / 256; ++i) {
      if (ks[i] >= 0) {
        const int b = ks[i] >> 8;
        const int r = atomicAdd(&lc[b], 1);
        pd[gb[b] + r] = ((uint)ks[i] << 16) | (uint)vs[i];
      }
    }
    return;
  }

  // ---- stmsg branch (R10 stmsg_kernel body) ----
  ushort* Sh = Sbuf;
  ushort* Sl = Sbuf + TEA * LSTR;
  const int bid = blockIdx.x - nScatter;
  const int row0 = bid * TEA;
  const int rem = Nn - row0;
  const int nrow = rem < TEA ? rem : TEA;

  STAGE_ROWS(X);
  __syncthreads();
  MFMA_PRELUDE(2);

  // ---- nt MLP -> stc ----
  ZERO_ACC(2);
  MFMA_LAYER(Wn1, Wn1 + 16384, 2);
  __syncthreads();
  HIDDEN_TO_LDS(Bn1, 2);
  __syncthreads();
  ZERO_ACC(2);
  MFMA_LAYER(Wn2, Wn2 + 16384, 2);

  float stc[2][2][4];
  {
    const float b2a = Bn2[w32 + l15];
    const float b2b = Bn2[w32 + 16 + l15];
    #pragma unroll
    for (int mt = 0; mt < 2; ++mt)
      #pragma unroll
      for (int nl = 0; nl < 2; ++nl) {
        const int col = w32 + nl * 16 + l15;
        const float bb = nl ? b2b : b2a;
        #pragma unroll
        for (int rg = 0; rg < 4; ++rg) {
          const int row = mt * 16 + q8 * 4 + rg;
          const float v = acc[mt][nl][rg] + bb;
          stc[mt][nl][rg] = v;
          if (row < nrow) st[(size_t)(row0 + row) * Dd + col] = v;
        }
      }
  }
  __syncthreads();  // hidden tile fully consumed

  // ---- fwd msg MLP on stc ----
  STC_TO_LDS(2);
  __syncthreads();
  ZERO_ACC(2);
  MFMA_LAYER(pf.p1, pf.p1 + 16384, 2);
  __syncthreads();
  HIDDEN_TO_LDS(pf.pb1, 2);
  __syncthreads();
  ZERO_ACC(2);
  MFMA_LAYER(pf.p2, pf.p2 + 16384, 2);
  {
    const float b2a = pf.pb2[w32 + l15];
    const float b2b = pf.pb2[w32 + 16 + l15];
    #pragma unroll
    for (int mt = 0; mt < 2; ++mt)
      #pragma unroll
      for (int nl = 0; nl < 2; ++nl) {
        const int col = w32 + nl * 16 + l15;
        const float bb = nl ? b2b : b2a;
        #pragma unroll
        for (int rg = 0; rg < 4; ++rg) {
          const int row = mt * 16 + q8 * 4 + rg;
          if (row < nrow)
            Mf[(size_t)(row0 + row) * Dd + col] =
                f32_to_bf16_rtn(fmaxf(acc[mt][nl][rg] + bb, 0.f));
        }
      }
  }
  __syncthreads();

  // ---- bwd msg MLP on stc ----
  STC_TO_LDS(2);
  __syncthreads();
  ZERO_ACC(2);
  MFMA_LAYER(pb.p1, pb.p1 + 16384, 2);
  __syncthreads();
  HIDDEN_TO_LDS(pb.pb1, 2);
  __syncthreads();
  ZERO_ACC(2);
  MFMA_LAYER(pb.p2, pb.p2 + 16384, 2);
  {
    const float b2a = pb.pb2[w32 + l15];
    const float b2b = pb.pb2[w32 + 16 + l15];
    #pragma unroll
    for (int mt = 0; mt < 2; ++mt)
      #pragma unroll
      for (int nl = 0; nl < 2; ++nl) {
        const int col = w32 + nl * 16 + l15;
        const float bb = nl ? b2b : b2a;
        #pragma unroll
        for (int rg = 0; rg < 4; ++rg) {
          const int row = mt * 16 + q8 * 4 + rg;
          if (row < nrow)
            Mb[(size_t)(row0 + row) * Dd + col] =
                f32_to_bf16_rtn(fmaxf(acc[mt][nl][rg] + bb, 0.f));
        }
      }
  }
}

// LDS pair staging + 8-band src-ordered emit (band = src>>13). Writes colo
// directly to global (4B scatter within a 16KB L2-hot window).  [R10 exact]
__global__ __launch_bounds__(256) void csr_final(
    const uint* __restrict__ pairs, const int* __restrict__ bbase,
    int* __restrict__ rp, int* __restrict__ col_f, int* __restrict__ col_b)
{
  const int dirv = blockIdx.y;
  const int b = blockIdx.x;
  const int base = bbase[dirv * 257 + b];
  const int cnt = bbase[dirv * 257 + b + 1] - base;
  const uint* pd = pairs + (size_t)dirv * Ee + base;
  int* colo = dirv ? col_b : col_f;
  __shared__ int h[256];
  __shared__ int s[256];
  __shared__ uint pr[FCAP];   // staged pairs (22.5 KB)
  const int t = threadIdx.x;
  h[t] = 0;
  __syncthreads();
  const bool fits = (cnt <= FCAP);
  if (fits) {
    for (int i = t; i < cnt; i += 256) {
      const uint p = pd[i];
      pr[i] = p;
      atomicAdd(&h[(p >> 16) & 255], 1);
    }
  } else {
    for (int i = t; i < cnt; i += 256) atomicAdd(&h[(pd[i] >> 16) & 255], 1);
  }
  __syncthreads();
  const int v = h[t];
  s[t] = v;
  __syncthreads();
  for (int off = 1; off < 256; off <<= 1) {
    int x = s[t];
    if (t >= off) x += s[t - off];
    __syncthreads();
    s[t] = x;
    __syncthreads();
  }
  const int excl = s[t] - v;
  const int node = b * 256 + t;
  if (node < Nn) rp[dirv * (Nn + 1) + node] = base + excl;
  h[t] = excl;  // becomes per-node cursor
  __syncthreads();
  if (fits) {
    for (int band = 0; band < 8; ++band) {
      for (int i = t; i < cnt; i += 256) {
        const uint p = pr[i];
        const int vv = (int)(p & 0xffffu);
        if ((vv >> 13) == band) {
          const int k = (p >> 16) & 255;
          const int r = atomicAdd(&h[k], 1);
          colo[base + r] = vv;
        }
      }
      __syncthreads();
    }
  } else {
    // fallback (statistically unreachable): plain scatter
    for (int i = t; i < cnt; i += 256) {
      const uint p = pd[i];
      const int k = (p >> 16) & 255;
      const int r = atomicAdd(&h[k], 1);
      colo[base + r] = (int)(p & 0xffffu);
    }
  }
}

// ---------------------------------------------------------------------------
// Fused per-round kernel, dual direction (2*1563 blocks, TEA=32 rows)
// Phase A: 8 threads per node row; thread o8 owns the contiguous 32 B at
// byte offset o8*32 of each 256 B row (line-perfect). Edge-unrolled x4.
// ---------------------------------------------------------------------------
template <int DO_MSG>
__global__ __launch_bounds__(NT) void aggupdmsg_kernel(
    const ushort* __restrict__ Min_f, const ushort* __restrict__ Min_b,
    const int* __restrict__ rp_f, const int* __restrict__ rp_b,
    const int* __restrict__ col_f, const int* __restrict__ col_b,
    const float* __restrict__ st,
    ushort* __restrict__ RMf, ushort* __restrict__ RMb,
    float* __restrict__ RYf, float* __restrict__ RYb, int rstride,
    DirP pf, DirP pb, int nhalf)
{
  __shared__ __align__(16) ushort Sbuf[2 * TEA * LSTR];  // 17.4 KB
  ushort* Sh = Sbuf;
  ushort* Sl = Sbuf + TEA * LSTR;
  const int t = threadIdx.x;
  const int dir = blockIdx.x >= nhalf;
  const int row0 = (blockIdx.x - dir * nhalf) * TEA;
  const int rem = Nn - row0;
  const int nrow = rem < TEA ? rem : TEA;
  const DirP P = dir ? pb : pf;
  const ushort* Min = dir ? Min_b : Min_f;
  const int* rp = dir ? rp_b : rp_f;
  const int* col = dir ? col_b : col_f;
  ushort* RoutM = dir ? RMb : RMf;
  float* RoutY = dir ? RYb : RYf;
  const int sink = dir ? 0 : (Nn - 1);

  // ---- phase A: gather-sum of bf16 M rows, f32 accumulate ----
  {
    const int nr = t >> 3;           // tile row, 8 threads per row
    const int o8 = t & 7;            // 32B sub-chunk id (cols o8*16..+15)
    float4 za[4];
    #pragma unroll
    for (int i = 0; i < 4; ++i) za[i] = make_float4(0.f, 0.f, 0.f, 0.f);
    if (nr < nrow) {
      const int gnode = row0 + nr;
      int e = rp[gnode];
      const int ee = rp[gnode + 1];
      const ushort* Mo = Min + o8 * 16;   // o8*32 bytes into each row
      for (; e + 3 < ee; e += 4) {   // 8 independent 16B loads in flight
        const int c0 = col[e];
        const int c1 = col[e + 1];
        const int c2 = col[e + 2];
        const int c3 = col[e + 3];
        const ushort* r0 = Mo + (size_t)c0 * Dd;
        const ushort* r1 = Mo + (size_t)c1 * Dd;
        const ushort* r2 = Mo + (size_t)c2 * Dd;
        const ushort* r3 = Mo + (size_t)c3 * Dd;
        uint4 a0 = *(const uint4*)(r0), b0 = *(const uint4*)(r0 + 8);
        uint4 a1 = *(const uint4*)(r1), b1 = *(const uint4*)(r1 + 8);
        uint4 a2 = *(const uint4*)(r2), b2 = *(const uint4*)(r2 + 8);
        uint4 a3 = *(const uint4*)(r3), b3 = *(const uint4*)(r3 + 8);
        acc8(a0, za[0], za[1]); acc8(b0, za[2], za[3]);
        acc8(a1, za[0], za[1]); acc8(b1, za[2], za[3]);
        acc8(a2, za[0], za[1]); acc8(b2, za[2], za[3]);
        acc8(a3, za[0], za[1]); acc8(b3, za[2], za[3]);
      }
      for (; e < ee; ++e) {
        const ushort* r0 = Mo + (size_t)col[e] * Dd;
        acc8(*(const uint4*)(r0), za[0], za[1]);
        acc8(*(const uint4*)(r0 + 8), za[2], za[3]);
      }
    }
    #pragma unroll
    for (int k = 0; k < 4; ++k) {
      ushort4 hv, lv; float rm;
      hv.x = bfsplit(za[k].x, &rm); lv.x = bftrunc(rm);
      hv.y = bfsplit(za[k].y, &rm); lv.y = bftrunc(rm);
      hv.z = bfsplit(za[k].z, &rm); lv.z = bftrunc(rm);
      hv.w = bfsplit(za[k].w, &rm); lv.w = bftrunc(rm);
      const int c4 = o8 * 16 + k * 4;
      *(ushort4*)(&Sh[nr * LSTR + c4]) = hv;
      *(ushort4*)(&Sl[nr * LSTR + c4]) = lv;
    }
  }
  __syncthreads();

  MFMA_PRELUDE(2);

  // ---- phase B: update MLP ----
  ZERO_ACC(2);
  MFMA_LAYER(P.u1, P.u1 + 16384, 2);
  __syncthreads();
  HIDDEN_TO_LDS(P.ub1, 2);
  __syncthreads();
  ZERO_ACC(2);
  MFMA_LAYER(P.u2, P.u2 + 16384, 2);

  // y = st + relu(acc + ub2), y[sink-row contribution] zeroed
  {
    const float b2a = P.ub2[w32 + l15];
    const float b2b = P.ub2[w32 + 16 + l15];
    if (DO_MSG) __syncthreads();  // all hidden reads done before overwrite
    #pragma unroll
    for (int mt = 0; mt < 2; ++mt)
      #pragma unroll
      for (int nl = 0; nl < 2; ++nl) {
        const int col = w32 + nl * 16 + l15;
        const float bb = nl ? b2b : b2a;
        #pragma unroll
        for (int rg = 0; rg < 4; ++rg) {
          const int row = mt * 16 + q8 * 4 + rg;
          float v = 0.f;
          if (row < nrow) {
            const int gr = row0 + row;
            v = fmaxf(acc[mt][nl][rg] + bb, 0.f);
            if (gr == sink) v = 0.f;
            v += st[(size_t)gr * Dd + col];
          }
          if (DO_MSG) {
            float rm;
            const ushort hh = bfsplit(v, &rm);
            const int off = row * LSTR + col;
            Sh[off] = hh;
            Sl[off] = bftrunc(rm);
          } else if (row < nrow) {
            RoutY[(size_t)(row0 + row) * rstride + col] = v;
          }
        }
      }
  }

  if (DO_MSG) {
    __syncthreads();
    // ---- phase C: msg MLP on y-tile ----
    ZERO_ACC(2);
    MFMA_LAYER(P.p1, P.p1 + 16384, 2);
    __syncthreads();
    HIDDEN_TO_LDS(P.pb1, 2);
    __syncthreads();
    ZERO_ACC(2);
    MFMA_LAYER(P.p2, P.p2 + 16384, 2);

    const float b2a = P.pb2[w32 + l15];
    const float b2b = P.pb2[w32 + 16 + l15];
    #pragma unroll
    for (int mt = 0; mt < 2; ++mt)
      #pragma unroll
      for (int nl = 0; nl < 2; ++nl) {
        const int col = w32 + nl * 16 + l15;
        const float bb = nl ? b2b : b2a;
        #pragma unroll
        for (int rg = 0; rg < 4; ++rg) {
          const int row = mt * 16 + q8 * 4 + rg;
          if (row < nrow)
            RoutM[(size_t)(row0 + row) * Dd + col] =
                f32_to_bf16_rtn(fmaxf(acc[mt][nl][rg] + bb, 0.f));
        }
      }
  }
}

// ---------------------------------------------------------------------------
extern "C" void kernel_launch(void* const* d_in, const int* in_sizes, int n_in,
                              void* d_out, int out_size, void* d_ws, size_t ws_size,
                              hipStream_t stream)
{
  const float* feat = (const float*)d_in[0];
  const int*   src  = (const int*)d_in[1];
  const int*   dst  = (const int*)d_in[2];

  const float* W[5][4];
  for (int p = 0; p < 5; ++p)
    for (int q = 0; q < 4; ++q)
      W[p][q] = (const float*)d_in[3 + p * 4 + q];

  // workspace: st(f32) + 4x bf16 M arrays + CSR + packed weights
  float* st = (float*)d_ws;                          // [N,D] f32
  ushort* Mp_f = (ushort*)(st + (size_t)Nn * Dd);    // ping fwd [N,D] bf16
  ushort* Mp_b = Mp_f + (size_t)Nn * Dd;             // ping bwd
  ushort* Mq_f = Mp_b + (size_t)Nn * Dd;             // pong fwd
  ushort* Mq_b = Mq_f + (size_t)Nn * Dd;             // pong bwd
  int* ip       = (int*)(Mq_b + (size_t)Nn * Dd);
  int* rp_f     = ip;                 ip += Nn + 1;  // rp_b contiguous after
  int* rp_b     = ip;                 ip += Nn + 1;
  int* col_f    = ip;                 ip += Ee;
  int* col_b    = ip;                 ip += Ee;
  int* bcnt     = ip;                 ip += 2 * 256;
  int* bbase    = ip;                 ip += 2 * 257;
  int* bcur     = ip;                 ip += 2 * 256;
  ushort* Wp = (ushort*)(((uintptr_t)ip + 63) & ~(uintptr_t)63);  // 640 KB
  float* out = (float*)d_out;                        // [N, 2D] f32

  // pairs buffer (6.4 MB) aliases the Mq pong region: CSR build completes
  // (stream-ordered) before round 1 writes Mq.
  uint* pairs = (uint*)Mq_f;

  const int aggBlocks  = (Nn + TEA - 1) / TEA;    // 1563 tiles
  const int dualBlocks = 2 * aggBlocks;           // 3126
  const int nScatter   = 2 * SB;                  // 782

  WPtrs wpk;  // slots: 2p = W[p].w1, 2p+1 = W[p].w2
  for (int p = 0; p < 5; ++p) { wpk.w[2 * p] = W[p][0]; wpk.w[2 * p + 1] = W[p][2]; }

  #define WS(m) (Wp + (size_t)(m) * WSLOT)
  // fwd: upd = fu (p=2), msg = fp (p=1); bwd: upd = bu (p=4), msg = bp (p=3)
  DirP Pf = { WS(4), WS(5), WS(2), WS(3), W[2][1], W[2][3], W[1][1], W[1][3] };
  DirP Pb = { WS(8), WS(9), WS(6), WS(7), W[4][1], W[4][3], W[3][1], W[3][3] };

  // ---- CSR build (R10-verified) + fused scatter/stmsg ----
  hipMemsetAsync(bcnt, 0, 2 * 256 * sizeof(int), stream);
  csr_count<<<dim3(SB, 2), 256, 0, stream>>>(src, dst, bcnt);
  csr_scan_pack<<<641, 256, 0, stream>>>(bcnt, bbase, bcur, rp_f, wpk, Wp);
  scatter_stmsg_kernel<<<nScatter + aggBlocks, NT, 0, stream>>>(
      src, dst, bcur, pairs, feat, WS(0), WS(1), W[0][1], W[0][3],
      Pf, Pb, st, Mp_f, Mp_b, nScatter);
  csr_final<<<dim3(NBUK, 2), 256, 0, stream>>>(pairs, bbase, rp_f, col_f, col_b);

  // ---- round 1: agg+upd+msg, ping -> pong ----
  aggupdmsg_kernel<1><<<dualBlocks, NT, 0, stream>>>(
      Mp_f, Mp_b, rp_f, rp_b, col_f, col_b, st,
      Mq_f, Mq_b, nullptr, nullptr, 0, Pf, Pb, aggBlocks);

  // ---- round 2: agg+upd+msg, pong -> ping ----
  aggupdmsg_kernel<1><<<dualBlocks, NT, 0, stream>>>(
      Mq_f, Mq_b, rp_f, rp_b, col_f, col_b, st,
      Mp_f, Mp_b, nullptr, nullptr, 0, Pf, Pb, aggBlocks);

  // ---- round 3 (final): agg+upd, ping -> y into out column-halves ----
  aggupdmsg_kernel<0><<<dualBlocks, NT, 0, stream>>>(
      Mp_f, Mp_b, rp_f, rp_b, col_f, col_b, st,
      nullptr, nullptr, out, out + Dd, 2 * Dd, Pf, Pb, aggBlocks);

  #undef WS
}